// Round 1
// baseline (926.776 us; speedup 1.0000x reference)
//
#include <hip/hip_runtime.h>
#include <math.h>

#define EPSF 1e-7f

struct Scalars { double mse_num, mse_den, pv_sum, pv_cnt, phys_sum; };

__global__ void zero_scalars_kernel(double* s) {
    int i = threadIdx.x;
    if (i < 5) s[i] = 0.0;
}

// Block-wide sum reduction (valid on thread 0). blockDim.x must be <= 512, mult of 64.
__device__ double blockReduceSum(double v) {
    __shared__ double red[8];
    #pragma unroll
    for (int off = 32; off > 0; off >>= 1)
        v += __shfl_down(v, off, 64);
    int lane = threadIdx.x & 63;
    int wid  = threadIdx.x >> 6;
    __syncthreads();                 // protect shared reuse across calls
    if (lane == 0) red[wid] = v;
    __syncthreads();
    if (threadIdx.x == 0) {
        double s = 0.0;
        int nw = blockDim.x >> 6;
        for (int w = 0; w < nw; ++w) s += red[w];
        v = s;
    }
    return v;
}

// Pass 1: per-node — MSE terms, PV terms, and seed calc[i] = real_pq[i].
__global__ void pass1_nodes(const float2* __restrict__ pred,
                            const float4* __restrict__ ty,
                            const float4* __restrict__ mask,
                            const int*    __restrict__ bus,
                            const float*  __restrict__ tvm,
                            const float*  __restrict__ xymean,
                            const float*  __restrict__ xystd,
                            float2*       __restrict__ calc,
                            Scalars* sc, int n)
{
    float xs0 = xystd[0] + EPSF, xs1 = xystd[1] + EPSF;
    float xs2 = xystd[2] + EPSF, xs3 = xystd[3] + EPSF;
    float xm0 = xymean[0], xm1 = xymean[1], xm2 = xymean[2], xm3 = xymean[3];

    double mse_num = 0.0, mse_den = 0.0, pv_sum = 0.0, pv_cnt = 0.0;
    int stride = gridDim.x * blockDim.x;
    for (int i = blockIdx.x * blockDim.x + threadIdx.x; i < n; i += stride) {
        float2 p = pred[i];
        float4 t = ty[i];
        float4 m = mask[i];
        float d0 = p.x - t.z, d1 = p.y - t.w;
        mse_num += (double)(d0 * d0 * m.z + d1 * d1 * m.w);
        mse_den += (double)(m.z + m.w);
        // real_pq seeds the flow accumulator
        calc[i] = make_float2(t.x * xs0 + xm0, t.y * xs1 + xm1);
        // PV loss
        float er0 = p.x * xs2 + xm2;
        float er1 = p.y * xs3 + xm3;
        float vmsq = er0 * er0 + er1 * er1;
        if (bus[i] == 1) {
            float tv = tvm[i];
            pv_sum += (double)fabsf(vmsq - tv * tv);
            pv_cnt += 1.0;
        }
    }
    mse_num = blockReduceSum(mse_num);
    mse_den = blockReduceSum(mse_den);
    pv_sum  = blockReduceSum(pv_sum);
    pv_cnt  = blockReduceSum(pv_cnt);
    if (threadIdx.x == 0) {
        atomicAdd(&sc->mse_num, mse_num);
        atomicAdd(&sc->mse_den, mse_den);
        atomicAdd(&sc->pv_sum,  pv_sum);
        atomicAdd(&sc->pv_cnt,  pv_cnt);
    }
}

// Pass 2: per-edge — both directed P/Q messages, atomic accumulate into calc.
__global__ void pass2_edges(const int*    __restrict__ ei,    // (2, E)
                            const float2* __restrict__ ea,    // (E, 2)
                            const float2* __restrict__ pred,  // (N, 2)
                            const float*  __restrict__ emean,
                            const float*  __restrict__ estd,
                            float*        __restrict__ calc,  // 2*N floats
                            int nE)
{
    float es0 = estd[0] + EPSF, es1 = estd[1] + EPSF;
    float em0 = emean[0], em1 = emean[1];
    int stride = gridDim.x * blockDim.x;
    for (int k = blockIdx.x * blockDim.x + threadIdx.x; k < nE; k += stride) {
        int a = ei[k];
        int b = ei[nE + k];
        float2 at = ea[k];
        float g  = at.x * es0 + em0;
        float bb = at.y * es1 + em1;
        float2 pa = pred[a];
        float2 pb = pred[b];
        float term1 = pa.x * pb.x + pa.y * pb.y;          // e_i e_j + f_i f_j
        float term2 = pa.y * pb.x - pa.x * pb.y;          // f_i e_j - e_i f_j (i=a)
        float vsa = pa.x * pa.x + pa.y * pa.y;
        float vsb = pb.x * pb.x + pb.y * pb.y;
        // forward: i=a, j=b
        float Pa =  g  * (vsa - term1) - bb * term2;
        float Qa = -bb * (vsa - term1) - g  * term2;
        // reverse: i=b, j=a  (term1 symmetric, term2 negates)
        float Pb =  g  * (vsb - term1) + bb * term2;
        float Qb = -bb * (vsb - term1) + g  * term2;
        unsafeAtomicAdd(&calc[2 * (size_t)a],     Pa);
        unsafeAtomicAdd(&calc[2 * (size_t)a + 1], Qa);
        unsafeAtomicAdd(&calc[2 * (size_t)b],     Pb);
        unsafeAtomicAdd(&calc[2 * (size_t)b + 1], Qb);
    }
}

// Pass 3: sum of squares of (real_pq + flow_sum).
__global__ void pass3_phys(const float2* __restrict__ calc, Scalars* sc, int n)
{
    double s = 0.0;
    int stride = gridDim.x * blockDim.x;
    for (int i = blockIdx.x * blockDim.x + threadIdx.x; i < n; i += stride) {
        float2 c = calc[i];
        s += (double)c.x * (double)c.x + (double)c.y * (double)c.y;
    }
    s = blockReduceSum(s);
    if (threadIdx.x == 0) atomicAdd(&sc->phys_sum, s);
}

__global__ void finalize_kernel(const Scalars* __restrict__ sc, float* __restrict__ out, int n)
{
    if (threadIdx.x == 0 && blockIdx.x == 0) {
        double mse  = sc->mse_num / (sc->mse_den + 1e-6);
        double phys = sc->phys_sum / (2.0 * (double)n);
        double pv   = (sc->pv_cnt > 0.0) ? (sc->pv_sum / fmax(sc->pv_cnt, 1.0)) : 0.0;
        double total = 0.8 * mse + 0.2 * phys + 0.1 * pv;
        out[0] = (float)total;
        out[1] = (float)mse;
        out[2] = (float)phys;
        out[3] = (float)pv;
    }
}

extern "C" void kernel_launch(void* const* d_in, const int* in_sizes, int n_in,
                              void* d_out, int out_size, void* d_ws, size_t ws_size,
                              hipStream_t stream) {
    const float2* pred   = (const float2*)d_in[0];
    const float4* ty     = (const float4*)d_in[1];
    const float4* mask   = (const float4*)d_in[2];
    const int*    ei     = (const int*)d_in[3];
    const float2* ea     = (const float2*)d_in[4];
    const int*    bus    = (const int*)d_in[5];
    const float*  tvm    = (const float*)d_in[6];
    const float*  xymean = (const float*)d_in[7];
    const float*  xystd  = (const float*)d_in[8];
    const float*  emean  = (const float*)d_in[9];
    const float*  estd   = (const float*)d_in[10];
    float* out = (float*)d_out;

    int n  = in_sizes[0] / 2;   // nodes
    int nE = in_sizes[3] / 2;   // edges

    // workspace: calc (2*n floats) then 5 doubles (8-byte aligned)
    float*   calc = (float*)d_ws;
    size_t calc_bytes = (size_t)2 * n * sizeof(float);
    Scalars* sc = (Scalars*)((char*)d_ws + ((calc_bytes + 7) & ~(size_t)7));

    const int BLK = 256;
    const int GRID = 2048;   // 2048 blocks * 4 waves = 8192 waves = full machine

    zero_scalars_kernel<<<1, 64, 0, stream>>>((double*)sc);
    pass1_nodes<<<GRID, BLK, 0, stream>>>(pred, ty, mask, bus, tvm, xymean, xystd,
                                          (float2*)calc, sc, n);
    pass2_edges<<<GRID, BLK, 0, stream>>>(ei, ea, pred, emean, estd, calc, nE);
    pass3_phys<<<GRID, BLK, 0, stream>>>((const float2*)calc, sc, n);
    finalize_kernel<<<1, 64, 0, stream>>>(sc, out, n);
}

// Round 2
// 617.781 us; speedup vs baseline: 1.5002x; 1.5002x over previous
//
#include <hip/hip_runtime.h>
#include <math.h>

#define EPSF 1e-7f

// ---- tunables for the binned-shuffle fast path ----
#define PART_BITS 12                 // partition = 4096 nodes
#define PART_SIZE (1 << PART_BITS)
#define MAXBINS   256                // static LDS counter array bound
#define K3GRID    512                // scatter blocks (bucket dimension)
#define CAP_MAX   96                 // per-(block,bin) bucket capacity target
#define CAP_MIN   32                 // below this, fall back to atomic path

struct Scalars { double mse_num, mse_den, pv_sum, pv_cnt, phys_sum; };

__global__ void zero_scalars_kernel(double* s) {
    int i = threadIdx.x;
    if (i < 5) s[i] = 0.0;
}

__global__ void zero_f32_kernel(float* p, int n) {
    int stride = gridDim.x * blockDim.x;
    for (int i = blockIdx.x * blockDim.x + threadIdx.x; i < n; i += stride)
        p[i] = 0.0f;
}

// Block-wide sum reduction (valid on thread 0). blockDim.x <= 512, mult of 64.
__device__ double blockReduceSum(double v) {
    __shared__ double red[8];
    #pragma unroll
    for (int off = 32; off > 0; off >>= 1)
        v += __shfl_down(v, off, 64);
    int lane = threadIdx.x & 63;
    int wid  = threadIdx.x >> 6;
    __syncthreads();
    if (lane == 0) red[wid] = v;
    __syncthreads();
    if (threadIdx.x == 0) {
        double s = 0.0;
        int nw = blockDim.x >> 6;
        for (int w = 0; w < nw; ++w) s += red[w];
        v = s;
    }
    return v;
}

// Pass 1: per-node — MSE terms, PV terms; optionally seed calc = real_pq (fallback path).
__global__ void pass1_nodes(const float2* __restrict__ pred,
                            const float4* __restrict__ ty,
                            const float4* __restrict__ mask,
                            const int*    __restrict__ bus,
                            const float*  __restrict__ tvm,
                            const float*  __restrict__ xymean,
                            const float*  __restrict__ xystd,
                            float2*       __restrict__ calc,
                            Scalars* sc, int n, int seed_calc)
{
    float xs0 = xystd[0] + EPSF, xs1 = xystd[1] + EPSF;
    float xs2 = xystd[2] + EPSF, xs3 = xystd[3] + EPSF;
    float xm0 = xymean[0], xm1 = xymean[1], xm2 = xymean[2], xm3 = xymean[3];

    double mse_num = 0.0, mse_den = 0.0, pv_sum = 0.0, pv_cnt = 0.0;
    int stride = gridDim.x * blockDim.x;
    for (int i = blockIdx.x * blockDim.x + threadIdx.x; i < n; i += stride) {
        float2 p = pred[i];
        float4 t = ty[i];
        float4 m = mask[i];
        float d0 = p.x - t.z, d1 = p.y - t.w;
        mse_num += (double)(d0 * d0 * m.z + d1 * d1 * m.w);
        mse_den += (double)(m.z + m.w);
        if (seed_calc)
            calc[i] = make_float2(t.x * xs0 + xm0, t.y * xs1 + xm1);
        float er0 = p.x * xs2 + xm2;
        float er1 = p.y * xs3 + xm3;
        float vmsq = er0 * er0 + er1 * er1;
        if (bus[i] == 1) {
            float tv = tvm[i];
            pv_sum += (double)fabsf(vmsq - tv * tv);
            pv_cnt += 1.0;
        }
    }
    mse_num = blockReduceSum(mse_num);
    mse_den = blockReduceSum(mse_den);
    pv_sum  = blockReduceSum(pv_sum);
    pv_cnt  = blockReduceSum(pv_cnt);
    if (threadIdx.x == 0) {
        atomicAdd(&sc->mse_num, mse_num);
        atomicAdd(&sc->mse_den, mse_den);
        atomicAdd(&sc->pv_sum,  pv_sum);
        atomicAdd(&sc->pv_cnt,  pv_cnt);
    }
}

// ---------------- fast path: binned shuffle ----------------

// K3: per-edge, compute both directed messages, append into per-(block,bin) buckets.
// Overflow (rank >= cap) goes through the device atomic path into calc (zeroed).
__global__ void scatter_edges(const int*    __restrict__ ei,    // (2, E)
                              const float2* __restrict__ ea,    // (E, 2)
                              const float2* __restrict__ pred,  // (N, 2)
                              const float*  __restrict__ emean,
                              const float*  __restrict__ estd,
                              float2*         __restrict__ bktPQ,
                              unsigned short* __restrict__ bktLD,
                              unsigned int*   __restrict__ gcnt,   // [K3GRID][nbins]
                              float*          __restrict__ calc,   // overflow accumulator, 2*N
                              int nE, int nbins, int cap)
{
    __shared__ unsigned int lcnt[MAXBINS];
    for (int b = threadIdx.x; b < nbins; b += blockDim.x) lcnt[b] = 0;
    __syncthreads();

    float es0 = estd[0] + EPSF, es1 = estd[1] + EPSF;
    float em0 = emean[0], em1 = emean[1];

    int stride = gridDim.x * blockDim.x;
    for (int k = blockIdx.x * blockDim.x + threadIdx.x; k < nE; k += stride) {
        int a = ei[k];
        int b = ei[nE + k];
        float2 at = ea[k];
        float g  = at.x * es0 + em0;
        float bb = at.y * es1 + em1;
        float2 pa = pred[a];
        float2 pb = pred[b];
        float term1 = pa.x * pb.x + pa.y * pb.y;
        float term2 = pa.y * pb.x - pa.x * pb.y;
        float vsa = pa.x * pa.x + pa.y * pa.y;
        float vsb = pb.x * pb.x + pb.y * pb.y;
        float Pa =  g  * (vsa - term1) - bb * term2;
        float Qa = -bb * (vsa - term1) - g  * term2;
        float Pb =  g  * (vsb - term1) + bb * term2;
        float Qb = -bb * (vsb - term1) + g  * term2;

        // append message (Pa,Qa) -> node a
        {
            int bin = a >> PART_BITS;
            unsigned int r = atomicAdd(&lcnt[bin], 1u);
            if (r < (unsigned)cap) {
                size_t s = ((size_t)blockIdx.x * nbins + bin) * cap + r;
                bktPQ[s] = make_float2(Pa, Qa);
                bktLD[s] = (unsigned short)(a & (PART_SIZE - 1));
            } else {
                unsafeAtomicAdd(&calc[2 * (size_t)a],     Pa);
                unsafeAtomicAdd(&calc[2 * (size_t)a + 1], Qa);
            }
        }
        // append message (Pb,Qb) -> node b
        {
            int bin = b >> PART_BITS;
            unsigned int r = atomicAdd(&lcnt[bin], 1u);
            if (r < (unsigned)cap) {
                size_t s = ((size_t)blockIdx.x * nbins + bin) * cap + r;
                bktPQ[s] = make_float2(Pb, Qb);
                bktLD[s] = (unsigned short)(b & (PART_SIZE - 1));
            } else {
                unsafeAtomicAdd(&calc[2 * (size_t)b],     Pb);
                unsafeAtomicAdd(&calc[2 * (size_t)b + 1], Qb);
            }
        }
    }
    __syncthreads();
    for (int b = threadIdx.x; b < nbins; b += blockDim.x)
        gcnt[(size_t)blockIdx.x * nbins + b] = min(lcnt[b], (unsigned)cap);
}

// K4: one block per partition — LDS accumulate, then fuse real_pq + overflow + square-sum.
__global__ void gather_partitions(const float2*         __restrict__ bktPQ,
                                  const unsigned short* __restrict__ bktLD,
                                  const unsigned int*   __restrict__ gcnt,
                                  const float*          __restrict__ calc,   // overflow
                                  const float4*         __restrict__ ty,
                                  const float*          __restrict__ xymean,
                                  const float*          __restrict__ xystd,
                                  Scalars* sc, int n, int nbins, int cap)
{
    __shared__ float accx[PART_SIZE];
    __shared__ float accy[PART_SIZE];
    __shared__ unsigned int cnts[K3GRID];

    int p = blockIdx.x;
    for (int i = threadIdx.x; i < PART_SIZE; i += blockDim.x) {
        accx[i] = 0.0f; accy[i] = 0.0f;
    }
    for (int b = threadIdx.x; b < K3GRID; b += blockDim.x)
        cnts[b] = gcnt[(size_t)b * nbins + p];
    __syncthreads();

    for (int b = 0; b < K3GRID; ++b) {
        int c = (int)cnts[b];
        size_t base = ((size_t)b * nbins + p) * cap;
        for (int t = threadIdx.x; t < c; t += blockDim.x) {
            float2 pq = bktPQ[base + t];
            int ld = bktLD[base + t];
            atomicAdd(&accx[ld], pq.x);
            atomicAdd(&accy[ld], pq.y);
        }
    }
    __syncthreads();

    float xs0 = xystd[0] + EPSF, xs1 = xystd[1] + EPSF;
    float xm0 = xymean[0], xm1 = xymean[1];
    double s = 0.0;
    int base_node = p << PART_BITS;
    for (int i = threadIdx.x; i < PART_SIZE; i += blockDim.x) {
        int g = base_node + i;
        if (g < n) {
            float4 t = ty[g];
            float vx = t.x * xs0 + xm0 + accx[i] + calc[2 * (size_t)g];
            float vy = t.y * xs1 + xm1 + accy[i] + calc[2 * (size_t)g + 1];
            s += (double)vx * (double)vx + (double)vy * (double)vy;
        }
    }
    s = blockReduceSum(s);
    if (threadIdx.x == 0) atomicAdd(&sc->phys_sum, s);
}

// ---------------- fallback path (R1): direct atomics ----------------

__global__ void pass2_edges(const int*    __restrict__ ei,
                            const float2* __restrict__ ea,
                            const float2* __restrict__ pred,
                            const float*  __restrict__ emean,
                            const float*  __restrict__ estd,
                            float*        __restrict__ calc,
                            int nE)
{
    float es0 = estd[0] + EPSF, es1 = estd[1] + EPSF;
    float em0 = emean[0], em1 = emean[1];
    int stride = gridDim.x * blockDim.x;
    for (int k = blockIdx.x * blockDim.x + threadIdx.x; k < nE; k += stride) {
        int a = ei[k];
        int b = ei[nE + k];
        float2 at = ea[k];
        float g  = at.x * es0 + em0;
        float bb = at.y * es1 + em1;
        float2 pa = pred[a];
        float2 pb = pred[b];
        float term1 = pa.x * pb.x + pa.y * pb.y;
        float term2 = pa.y * pb.x - pa.x * pb.y;
        float vsa = pa.x * pa.x + pa.y * pa.y;
        float vsb = pb.x * pb.x + pb.y * pb.y;
        float Pa =  g  * (vsa - term1) - bb * term2;
        float Qa = -bb * (vsa - term1) - g  * term2;
        float Pb =  g  * (vsb - term1) + bb * term2;
        float Qb = -bb * (vsb - term1) + g  * term2;
        unsafeAtomicAdd(&calc[2 * (size_t)a],     Pa);
        unsafeAtomicAdd(&calc[2 * (size_t)a + 1], Qa);
        unsafeAtomicAdd(&calc[2 * (size_t)b],     Pb);
        unsafeAtomicAdd(&calc[2 * (size_t)b + 1], Qb);
    }
}

__global__ void pass3_phys(const float2* __restrict__ calc, Scalars* sc, int n)
{
    double s = 0.0;
    int stride = gridDim.x * blockDim.x;
    for (int i = blockIdx.x * blockDim.x + threadIdx.x; i < n; i += stride) {
        float2 c = calc[i];
        s += (double)c.x * (double)c.x + (double)c.y * (double)c.y;
    }
    s = blockReduceSum(s);
    if (threadIdx.x == 0) atomicAdd(&sc->phys_sum, s);
}

__global__ void finalize_kernel(const Scalars* __restrict__ sc, float* __restrict__ out, int n)
{
    if (threadIdx.x == 0 && blockIdx.x == 0) {
        double mse  = sc->mse_num / (sc->mse_den + 1e-6);
        double phys = sc->phys_sum / (2.0 * (double)n);
        double pv   = (sc->pv_cnt > 0.0) ? (sc->pv_sum / fmax(sc->pv_cnt, 1.0)) : 0.0;
        double total = 0.8 * mse + 0.2 * phys + 0.1 * pv;
        out[0] = (float)total;
        out[1] = (float)mse;
        out[2] = (float)phys;
        out[3] = (float)pv;
    }
}

extern "C" void kernel_launch(void* const* d_in, const int* in_sizes, int n_in,
                              void* d_out, int out_size, void* d_ws, size_t ws_size,
                              hipStream_t stream) {
    const float2* pred   = (const float2*)d_in[0];
    const float4* ty     = (const float4*)d_in[1];
    const float4* mask   = (const float4*)d_in[2];
    const int*    ei     = (const int*)d_in[3];
    const float2* ea     = (const float2*)d_in[4];
    const int*    bus    = (const int*)d_in[5];
    const float*  tvm    = (const float*)d_in[6];
    const float*  xymean = (const float*)d_in[7];
    const float*  xystd  = (const float*)d_in[8];
    const float*  emean  = (const float*)d_in[9];
    const float*  estd   = (const float*)d_in[10];
    float* out = (float*)d_out;

    int n  = in_sizes[0] / 2;   // nodes
    int nE = in_sizes[3] / 2;   // edges
    int nbins = (n + PART_SIZE - 1) >> PART_BITS;

    // workspace layout: Scalars (64B) | calc (2n f32) | gcnt | bktPQ | bktLD
    char* base = (char*)d_ws;
    Scalars* sc = (Scalars*)base;
    size_t off = 64;
    float* calc = (float*)(base + off);
    off += (size_t)2 * n * sizeof(float);
    unsigned int* gcnt = (unsigned int*)(base + off);
    off += (size_t)K3GRID * nbins * sizeof(unsigned int);
    off = (off + 7) & ~(size_t)7;

    // adaptive bucket capacity
    int cap = 0;
    if (nbins <= MAXBINS && ws_size > off) {
        size_t avail = ws_size - off;
        size_t per_slot = sizeof(float2) + sizeof(unsigned short); // 10B
        size_t cap_fit = avail / ((size_t)K3GRID * nbins * per_slot);
        cap = (int)((cap_fit < CAP_MAX) ? cap_fit : CAP_MAX);
    }

    const int BLK = 256;
    const int GRID = 2048;

    if (cap >= CAP_MIN) {
        // ---- fast path: binned shuffle ----
        float2* bktPQ = (float2*)(base + off);
        off += (size_t)K3GRID * nbins * cap * sizeof(float2);
        unsigned short* bktLD = (unsigned short*)(base + off);

        zero_scalars_kernel<<<1, 64, 0, stream>>>((double*)sc);
        zero_f32_kernel<<<256, 256, 0, stream>>>(calc, 2 * n);   // overflow accumulator
        pass1_nodes<<<GRID, BLK, 0, stream>>>(pred, ty, mask, bus, tvm, xymean, xystd,
                                              (float2*)calc, sc, n, /*seed=*/0);
        scatter_edges<<<K3GRID, BLK, 0, stream>>>(ei, ea, pred, emean, estd,
                                                  bktPQ, bktLD, gcnt, calc, nE, nbins, cap);
        gather_partitions<<<nbins, BLK, 0, stream>>>(bktPQ, bktLD, gcnt, calc, ty,
                                                     xymean, xystd, sc, n, nbins, cap);
        finalize_kernel<<<1, 64, 0, stream>>>(sc, out, n);
    } else {
        // ---- fallback path: direct atomics (R1) ----
        zero_scalars_kernel<<<1, 64, 0, stream>>>((double*)sc);
        pass1_nodes<<<GRID, BLK, 0, stream>>>(pred, ty, mask, bus, tvm, xymean, xystd,
                                              (float2*)calc, sc, n, /*seed=*/1);
        pass2_edges<<<GRID, BLK, 0, stream>>>(ei, ea, pred, emean, estd, calc, nE);
        pass3_phys<<<GRID, BLK, 0, stream>>>((const float2*)calc, sc, n);
        finalize_kernel<<<1, 64, 0, stream>>>(sc, out, n);
    }
}

// Round 3
// 421.827 us; speedup vs baseline: 2.1971x; 1.4645x over previous
//
#include <hip/hip_runtime.h>
#include <math.h>

#define EPSF 1e-7f

// ---- tunables for the binned-shuffle fast path ----
#define PART_BITS 12                 // partition = 4096 nodes
#define PART_SIZE (1 << PART_BITS)
#define MAXBINS   256                // static LDS counter array bound
#define K3GRID    512                // scatter blocks (bucket dimension)
#define K3BLK     1024               // scatter block size: 512*1024 = 8192 waves = 100%
#define K4BLK     1024               // gather block size
#define CAP_MAX   96                 // per-(block,bin) bucket capacity target
#define CAP_MIN   32                 // below this, fall back to atomic path

struct Scalars { double mse_num, mse_den, pv_sum, pv_cnt, phys_sum; };

__global__ void zero_scalars_kernel(double* s) {
    int i = threadIdx.x;
    if (i < 5) s[i] = 0.0;
}

__global__ void zero_f32_kernel(float* p, int n) {
    int stride = gridDim.x * blockDim.x;
    for (int i = blockIdx.x * blockDim.x + threadIdx.x; i < n; i += stride)
        p[i] = 0.0f;
}

// Block-wide sum reduction (valid on thread 0). blockDim.x <= 1024, mult of 64.
__device__ double blockReduceSum(double v) {
    __shared__ double red[16];
    #pragma unroll
    for (int off = 32; off > 0; off >>= 1)
        v += __shfl_down(v, off, 64);
    int lane = threadIdx.x & 63;
    int wid  = threadIdx.x >> 6;
    __syncthreads();
    if (lane == 0) red[wid] = v;
    __syncthreads();
    if (threadIdx.x == 0) {
        double s = 0.0;
        int nw = blockDim.x >> 6;
        for (int w = 0; w < nw; ++w) s += red[w];
        v = s;
    }
    return v;
}

// Pass 1: per-node — MSE terms, PV terms; optionally seed calc = real_pq (fallback path).
__global__ void pass1_nodes(const float2* __restrict__ pred,
                            const float4* __restrict__ ty,
                            const float4* __restrict__ mask,
                            const int*    __restrict__ bus,
                            const float*  __restrict__ tvm,
                            const float*  __restrict__ xymean,
                            const float*  __restrict__ xystd,
                            float2*       __restrict__ calc,
                            Scalars* sc, int n, int seed_calc)
{
    float xs0 = xystd[0] + EPSF, xs1 = xystd[1] + EPSF;
    float xs2 = xystd[2] + EPSF, xs3 = xystd[3] + EPSF;
    float xm0 = xymean[0], xm1 = xymean[1], xm2 = xymean[2], xm3 = xymean[3];

    double mse_num = 0.0, mse_den = 0.0, pv_sum = 0.0, pv_cnt = 0.0;
    int stride = gridDim.x * blockDim.x;
    for (int i = blockIdx.x * blockDim.x + threadIdx.x; i < n; i += stride) {
        float2 p = pred[i];
        float4 t = ty[i];
        float4 m = mask[i];
        float d0 = p.x - t.z, d1 = p.y - t.w;
        mse_num += (double)(d0 * d0 * m.z + d1 * d1 * m.w);
        mse_den += (double)(m.z + m.w);
        if (seed_calc)
            calc[i] = make_float2(t.x * xs0 + xm0, t.y * xs1 + xm1);
        float er0 = p.x * xs2 + xm2;
        float er1 = p.y * xs3 + xm3;
        float vmsq = er0 * er0 + er1 * er1;
        if (bus[i] == 1) {
            float tv = tvm[i];
            pv_sum += (double)fabsf(vmsq - tv * tv);
            pv_cnt += 1.0;
        }
    }
    mse_num = blockReduceSum(mse_num);
    mse_den = blockReduceSum(mse_den);
    pv_sum  = blockReduceSum(pv_sum);
    pv_cnt  = blockReduceSum(pv_cnt);
    if (threadIdx.x == 0) {
        atomicAdd(&sc->mse_num, mse_num);
        atomicAdd(&sc->mse_den, mse_den);
        atomicAdd(&sc->pv_sum,  pv_sum);
        atomicAdd(&sc->pv_cnt,  pv_cnt);
    }
}

// ---------------- fast path: binned shuffle ----------------

// K3: per-edge, compute both directed messages, append into per-(block,bin) buckets.
// Overflow (rank >= cap) goes through the device atomic path into calc (zeroed).
__global__ __launch_bounds__(K3BLK)
void scatter_edges(const int*    __restrict__ ei,    // (2, E)
                   const float2* __restrict__ ea,    // (E, 2)
                   const float2* __restrict__ pred,  // (N, 2)
                   const float*  __restrict__ emean,
                   const float*  __restrict__ estd,
                   float2*         __restrict__ bktPQ,
                   unsigned short* __restrict__ bktLD,
                   unsigned int*   __restrict__ gcnt,   // [K3GRID][nbins]
                   float*          __restrict__ calc,   // overflow accumulator, 2*N
                   int nE, int nbins, int cap)
{
    __shared__ unsigned int lcnt[MAXBINS];
    for (int b = threadIdx.x; b < nbins; b += blockDim.x) lcnt[b] = 0;
    __syncthreads();

    float es0 = estd[0] + EPSF, es1 = estd[1] + EPSF;
    float em0 = emean[0], em1 = emean[1];

    int stride = gridDim.x * blockDim.x;
    for (int k = blockIdx.x * blockDim.x + threadIdx.x; k < nE; k += stride) {
        int a = ei[k];
        int b = ei[nE + k];
        float2 at = ea[k];
        float g  = at.x * es0 + em0;
        float bb = at.y * es1 + em1;
        float2 pa = pred[a];
        float2 pb = pred[b];
        float term1 = pa.x * pb.x + pa.y * pb.y;
        float term2 = pa.y * pb.x - pa.x * pb.y;
        float vsa = pa.x * pa.x + pa.y * pa.y;
        float vsb = pb.x * pb.x + pb.y * pb.y;
        float Pa =  g  * (vsa - term1) - bb * term2;
        float Qa = -bb * (vsa - term1) - g  * term2;
        float Pb =  g  * (vsb - term1) + bb * term2;
        float Qb = -bb * (vsb - term1) + g  * term2;

        // append message (Pa,Qa) -> node a
        {
            int bin = a >> PART_BITS;
            unsigned int r = atomicAdd(&lcnt[bin], 1u);
            if (r < (unsigned)cap) {
                size_t s = ((size_t)blockIdx.x * nbins + bin) * cap + r;
                bktPQ[s] = make_float2(Pa, Qa);
                bktLD[s] = (unsigned short)(a & (PART_SIZE - 1));
            } else {
                unsafeAtomicAdd(&calc[2 * (size_t)a],     Pa);
                unsafeAtomicAdd(&calc[2 * (size_t)a + 1], Qa);
            }
        }
        // append message (Pb,Qb) -> node b
        {
            int bin = b >> PART_BITS;
            unsigned int r = atomicAdd(&lcnt[bin], 1u);
            if (r < (unsigned)cap) {
                size_t s = ((size_t)blockIdx.x * nbins + bin) * cap + r;
                bktPQ[s] = make_float2(Pb, Qb);
                bktLD[s] = (unsigned short)(b & (PART_SIZE - 1));
            } else {
                unsafeAtomicAdd(&calc[2 * (size_t)b],     Pb);
                unsafeAtomicAdd(&calc[2 * (size_t)b + 1], Qb);
            }
        }
    }
    __syncthreads();
    for (int b = threadIdx.x; b < nbins; b += blockDim.x)
        gcnt[(size_t)blockIdx.x * nbins + b] = min(lcnt[b], (unsigned)cap);
}

// K4: one block per partition — wave-per-bucket LDS accumulate, then fuse
// real_pq + overflow + square-sum.
__global__ __launch_bounds__(K4BLK)
void gather_partitions(const float2*         __restrict__ bktPQ,
                       const unsigned short* __restrict__ bktLD,
                       const unsigned int*   __restrict__ gcnt,
                       const float*          __restrict__ calc,   // overflow
                       const float4*         __restrict__ ty,
                       const float*          __restrict__ xymean,
                       const float*          __restrict__ xystd,
                       Scalars* sc, int n, int nbins, int cap)
{
    __shared__ float accx[PART_SIZE];
    __shared__ float accy[PART_SIZE];
    __shared__ unsigned int cnts[K3GRID];

    int p = blockIdx.x;
    for (int i = threadIdx.x; i < PART_SIZE; i += blockDim.x) {
        accx[i] = 0.0f; accy[i] = 0.0f;
    }
    for (int b = threadIdx.x; b < K3GRID; b += blockDim.x)
        cnts[b] = gcnt[(size_t)b * nbins + p];
    __syncthreads();

    // wave-per-bucket: wave w handles buckets w, w+nw, ... (64 lanes per bucket)
    int lane = threadIdx.x & 63;
    int wid  = threadIdx.x >> 6;
    int nw   = blockDim.x >> 6;
    for (int b = wid; b < K3GRID; b += nw) {
        int c = (int)cnts[b];
        size_t base = ((size_t)b * nbins + p) * cap;
        for (int t = lane; t < c; t += 64) {
            float2 pq = bktPQ[base + t];
            int ld = bktLD[base + t];
            atomicAdd(&accx[ld], pq.x);
            atomicAdd(&accy[ld], pq.y);
        }
    }
    __syncthreads();

    float xs0 = xystd[0] + EPSF, xs1 = xystd[1] + EPSF;
    float xm0 = xymean[0], xm1 = xymean[1];
    double s = 0.0;
    int base_node = p << PART_BITS;
    for (int i = threadIdx.x; i < PART_SIZE; i += blockDim.x) {
        int g = base_node + i;
        if (g < n) {
            float4 t = ty[g];
            float vx = t.x * xs0 + xm0 + accx[i] + calc[2 * (size_t)g];
            float vy = t.y * xs1 + xm1 + accy[i] + calc[2 * (size_t)g + 1];
            s += (double)vx * (double)vx + (double)vy * (double)vy;
        }
    }
    s = blockReduceSum(s);
    if (threadIdx.x == 0) atomicAdd(&sc->phys_sum, s);
}

// ---------------- fallback path (R1): direct atomics ----------------

__global__ void pass2_edges(const int*    __restrict__ ei,
                            const float2* __restrict__ ea,
                            const float2* __restrict__ pred,
                            const float*  __restrict__ emean,
                            const float*  __restrict__ estd,
                            float*        __restrict__ calc,
                            int nE)
{
    float es0 = estd[0] + EPSF, es1 = estd[1] + EPSF;
    float em0 = emean[0], em1 = emean[1];
    int stride = gridDim.x * blockDim.x;
    for (int k = blockIdx.x * blockDim.x + threadIdx.x; k < nE; k += stride) {
        int a = ei[k];
        int b = ei[nE + k];
        float2 at = ea[k];
        float g  = at.x * es0 + em0;
        float bb = at.y * es1 + em1;
        float2 pa = pred[a];
        float2 pb = pred[b];
        float term1 = pa.x * pb.x + pa.y * pb.y;
        float term2 = pa.y * pb.x - pa.x * pb.y;
        float vsa = pa.x * pa.x + pa.y * pa.y;
        float vsb = pb.x * pb.x + pb.y * pb.y;
        float Pa =  g  * (vsa - term1) - bb * term2;
        float Qa = -bb * (vsa - term1) - g  * term2;
        float Pb =  g  * (vsb - term1) + bb * term2;
        float Qb = -bb * (vsb - term1) + g  * term2;
        unsafeAtomicAdd(&calc[2 * (size_t)a],     Pa);
        unsafeAtomicAdd(&calc[2 * (size_t)a + 1], Qa);
        unsafeAtomicAdd(&calc[2 * (size_t)b],     Pb);
        unsafeAtomicAdd(&calc[2 * (size_t)b + 1], Qb);
    }
}

__global__ void pass3_phys(const float2* __restrict__ calc, Scalars* sc, int n)
{
    double s = 0.0;
    int stride = gridDim.x * blockDim.x;
    for (int i = blockIdx.x * blockDim.x + threadIdx.x; i < n; i += stride) {
        float2 c = calc[i];
        s += (double)c.x * (double)c.x + (double)c.y * (double)c.y;
    }
    s = blockReduceSum(s);
    if (threadIdx.x == 0) atomicAdd(&sc->phys_sum, s);
}

__global__ void finalize_kernel(const Scalars* __restrict__ sc, float* __restrict__ out, int n)
{
    if (threadIdx.x == 0 && blockIdx.x == 0) {
        double mse  = sc->mse_num / (sc->mse_den + 1e-6);
        double phys = sc->phys_sum / (2.0 * (double)n);
        double pv   = (sc->pv_cnt > 0.0) ? (sc->pv_sum / fmax(sc->pv_cnt, 1.0)) : 0.0;
        double total = 0.8 * mse + 0.2 * phys + 0.1 * pv;
        out[0] = (float)total;
        out[1] = (float)mse;
        out[2] = (float)phys;
        out[3] = (float)pv;
    }
}

extern "C" void kernel_launch(void* const* d_in, const int* in_sizes, int n_in,
                              void* d_out, int out_size, void* d_ws, size_t ws_size,
                              hipStream_t stream) {
    const float2* pred   = (const float2*)d_in[0];
    const float4* ty     = (const float4*)d_in[1];
    const float4* mask   = (const float4*)d_in[2];
    const int*    ei     = (const int*)d_in[3];
    const float2* ea     = (const float2*)d_in[4];
    const int*    bus    = (const int*)d_in[5];
    const float*  tvm    = (const float*)d_in[6];
    const float*  xymean = (const float*)d_in[7];
    const float*  xystd  = (const float*)d_in[8];
    const float*  emean  = (const float*)d_in[9];
    const float*  estd   = (const float*)d_in[10];
    float* out = (float*)d_out;

    int n  = in_sizes[0] / 2;   // nodes
    int nE = in_sizes[3] / 2;   // edges
    int nbins = (n + PART_SIZE - 1) >> PART_BITS;

    // workspace layout: Scalars (64B) | calc (2n f32) | gcnt | bktPQ | bktLD
    char* base = (char*)d_ws;
    Scalars* sc = (Scalars*)base;
    size_t off = 64;
    float* calc = (float*)(base + off);
    off += (size_t)2 * n * sizeof(float);
    unsigned int* gcnt = (unsigned int*)(base + off);
    off += (size_t)K3GRID * nbins * sizeof(unsigned int);
    off = (off + 7) & ~(size_t)7;

    // adaptive bucket capacity
    int cap = 0;
    if (nbins <= MAXBINS && ws_size > off) {
        size_t avail = ws_size - off;
        size_t per_slot = sizeof(float2) + sizeof(unsigned short); // 10B
        size_t cap_fit = avail / ((size_t)K3GRID * nbins * per_slot);
        cap = (int)((cap_fit < CAP_MAX) ? cap_fit : CAP_MAX);
    }

    const int BLK = 256;
    const int GRID = 2048;

    if (cap >= CAP_MIN) {
        // ---- fast path: binned shuffle ----
        float2* bktPQ = (float2*)(base + off);
        off += (size_t)K3GRID * nbins * cap * sizeof(float2);
        unsigned short* bktLD = (unsigned short*)(base + off);

        zero_scalars_kernel<<<1, 64, 0, stream>>>((double*)sc);
        zero_f32_kernel<<<2048, 256, 0, stream>>>(calc, 2 * n);   // overflow accumulator
        pass1_nodes<<<GRID, BLK, 0, stream>>>(pred, ty, mask, bus, tvm, xymean, xystd,
                                              (float2*)calc, sc, n, /*seed=*/0);
        scatter_edges<<<K3GRID, K3BLK, 0, stream>>>(ei, ea, pred, emean, estd,
                                                    bktPQ, bktLD, gcnt, calc, nE, nbins, cap);
        gather_partitions<<<nbins, K4BLK, 0, stream>>>(bktPQ, bktLD, gcnt, calc, ty,
                                                       xymean, xystd, sc, n, nbins, cap);
        finalize_kernel<<<1, 64, 0, stream>>>(sc, out, n);
    } else {
        // ---- fallback path: direct atomics (R1) ----
        zero_scalars_kernel<<<1, 64, 0, stream>>>((double*)sc);
        pass1_nodes<<<GRID, BLK, 0, stream>>>(pred, ty, mask, bus, tvm, xymean, xystd,
                                              (float2*)calc, sc, n, /*seed=*/1);
        pass2_edges<<<GRID, BLK, 0, stream>>>(ei, ea, pred, emean, estd, calc, nE);
        pass3_phys<<<GRID, BLK, 0, stream>>>((const float2*)calc, sc, n);
        finalize_kernel<<<1, 64, 0, stream>>>(sc, out, n);
    }
}

// Round 4
// 358.721 us; speedup vs baseline: 2.5836x; 1.1759x over previous
//
#include <hip/hip_runtime.h>
#include <math.h>

#define EPSF 1e-7f

#define K3GRID  512        // scatter blocks (bucket dimension)
#define K3BLK   1024       // 512*16 waves = 8192 = 100% of wave slots
#define K4BLK   1024
#define MAXBINS 512        // static LDS counter bound in scatter

struct Scalars { double mse_num, mse_den, pv_sum, pv_cnt, phys_sum; };

__global__ void zero_scalars_kernel(double* s) {
    int i = threadIdx.x;
    if (i < 5) s[i] = 0.0;
}

// Block-wide sum reduction (valid on thread 0). blockDim.x <= 1024, mult of 64.
__device__ double blockReduceSum(double v) {
    __shared__ double red[16];
    #pragma unroll
    for (int off = 32; off > 0; off >>= 1)
        v += __shfl_down(v, off, 64);
    int lane = threadIdx.x & 63;
    int wid  = threadIdx.x >> 6;
    __syncthreads();
    if (lane == 0) red[wid] = v;
    __syncthreads();
    if (threadIdx.x == 0) {
        double s = 0.0;
        int nw = blockDim.x >> 6;
        for (int w = 0; w < nw; ++w) s += red[w];
        v = s;
    }
    return v;
}

// Pass 1: per-node — MSE terms, PV terms; writes calc = real_pq (seed=1) or zeros (seed=0).
__global__ void pass1_nodes(const float2* __restrict__ pred,
                            const float4* __restrict__ ty,
                            const float4* __restrict__ mask,
                            const int*    __restrict__ bus,
                            const float*  __restrict__ tvm,
                            const float*  __restrict__ xymean,
                            const float*  __restrict__ xystd,
                            float2*       __restrict__ calc,
                            Scalars* sc, int n, int seed_calc)
{
    float xs0 = xystd[0] + EPSF, xs1 = xystd[1] + EPSF;
    float xs2 = xystd[2] + EPSF, xs3 = xystd[3] + EPSF;
    float xm0 = xymean[0], xm1 = xymean[1], xm2 = xymean[2], xm3 = xymean[3];

    double mse_num = 0.0, mse_den = 0.0, pv_sum = 0.0, pv_cnt = 0.0;
    int stride = gridDim.x * blockDim.x;
    for (int i = blockIdx.x * blockDim.x + threadIdx.x; i < n; i += stride) {
        float2 p = pred[i];
        float4 t = ty[i];
        float4 m = mask[i];
        float d0 = p.x - t.z, d1 = p.y - t.w;
        mse_num += (double)(d0 * d0 * m.z + d1 * d1 * m.w);
        mse_den += (double)(m.z + m.w);
        calc[i] = seed_calc ? make_float2(t.x * xs0 + xm0, t.y * xs1 + xm1)
                            : make_float2(0.0f, 0.0f);
        float er0 = p.x * xs2 + xm2;
        float er1 = p.y * xs3 + xm3;
        float vmsq = er0 * er0 + er1 * er1;
        if (bus[i] == 1) {
            float tv = tvm[i];
            pv_sum += (double)fabsf(vmsq - tv * tv);
            pv_cnt += 1.0;
        }
    }
    mse_num = blockReduceSum(mse_num);
    mse_den = blockReduceSum(mse_den);
    pv_sum  = blockReduceSum(pv_sum);
    pv_cnt  = blockReduceSum(pv_cnt);
    if (threadIdx.x == 0) {
        atomicAdd(&sc->mse_num, mse_num);
        atomicAdd(&sc->mse_den, mse_den);
        atomicAdd(&sc->pv_sum,  pv_sum);
        atomicAdd(&sc->pv_cnt,  pv_cnt);
    }
}

// ---------------- fast path: index-binning shuffle ----------------
// Record: [lid:12][other:20][edge:22]  (requires n <= 2^20, nE <= 2^22)

__device__ __forceinline__ void msg_compute(float2 ps, float2 po, float2 at,
                                            float es0, float es1, float em0, float em1,
                                            float& P, float& Q)
{
    float g  = at.x * es0 + em0;
    float bb = at.y * es1 + em1;
    float t1 = ps.x * po.x + ps.y * po.y;
    float t2 = ps.y * po.x - ps.x * po.y;
    float vs = ps.x * ps.x + ps.y * ps.y;
    P =  g  * (vs - t1) - bb * t2;
    Q = -bb * (vs - t1) - g  * t2;
}

// K3: bin endpoint records. No pred/ea reads on the main path.
__global__ __launch_bounds__(K3BLK)
void scatter_idx(const int*    __restrict__ ei,    // (2, E)
                 const float2* __restrict__ ea,
                 const float2* __restrict__ pred,
                 const float*  __restrict__ emean,
                 const float*  __restrict__ estd,
                 unsigned long long* __restrict__ bkt,
                 unsigned int*       __restrict__ gcnt,   // [K3GRID][nbins]
                 float*              __restrict__ calc,   // overflow accumulator
                 int nE, int nbins, int cap, int part_bits)
{
    __shared__ unsigned int lcnt[MAXBINS];
    for (int i = threadIdx.x; i < nbins; i += blockDim.x) lcnt[i] = 0;
    __syncthreads();

    float es0 = estd[0] + EPSF, es1 = estd[1] + EPSF;
    float em0 = emean[0], em1 = emean[1];
    unsigned lmask = (1u << part_bits) - 1u;

    int tid = blockIdx.x * blockDim.x + threadIdx.x;
    int stride = gridDim.x * blockDim.x;
    int npair = (nE + 1) >> 1;
    for (int q = tid; q < npair; q += stride) {
        int k0 = q * 2;
        int2 av, bv;
        if (k0 + 1 < nE) {
            av = ((const int2*)ei)[q];
            bv = ((const int2*)(ei + nE))[q];
        } else {
            av.x = ei[k0]; av.y = 0;
            bv.x = ei[nE + k0]; bv.y = 0;
        }
        #pragma unroll
        for (int j = 0; j < 2; ++j) {
            int k = k0 + j;
            if (k >= nE) break;
            int a = j ? av.y : av.x;
            int b = j ? bv.y : bv.x;
            // record toward a (self=a, other=b), then toward b
            #pragma unroll
            for (int d = 0; d < 2; ++d) {
                int self  = d ? b : a;
                int other = d ? a : b;
                int bin = self >> part_bits;
                unsigned r = atomicAdd(&lcnt[bin], 1u);
                if (r < (unsigned)cap) {
                    unsigned long long rec =
                        ((unsigned long long)((unsigned)self & lmask) << 42) |
                        ((unsigned long long)(unsigned)other << 22) |
                        (unsigned long long)(unsigned)k;
                    bkt[((size_t)blockIdx.x * nbins + bin) * cap + r] = rec;
                } else {
                    // rare overflow: compute message now, device atomic
                    float2 ps = pred[self];
                    float2 po = pred[other];
                    float2 at = ea[k];
                    float P, Q;
                    msg_compute(ps, po, at, es0, es1, em0, em1, P, Q);
                    unsafeAtomicAdd(&calc[2 * (size_t)self],     P);
                    unsafeAtomicAdd(&calc[2 * (size_t)self + 1], Q);
                }
            }
        }
    }
    __syncthreads();
    for (int i = threadIdx.x; i < nbins; i += blockDim.x)
        gcnt[(size_t)blockIdx.x * nbins + i] = min(lcnt[i], (unsigned)cap);
}

// K4: one block per partition — recompute messages, LDS accumulate, fuse square-sum.
template<int PB, int CAP>
__global__ __launch_bounds__(K4BLK)
void gather_t(const unsigned long long* __restrict__ bkt,
              const unsigned int*       __restrict__ gcnt,
              const float2* __restrict__ pred,
              const float2* __restrict__ ea,
              const float*  __restrict__ emean,
              const float*  __restrict__ estd,
              const float*  __restrict__ calc,   // overflow
              const float4* __restrict__ ty,
              const float*  __restrict__ xymean,
              const float*  __restrict__ xystd,
              Scalars* sc, int n, int nbins)
{
    constexpr int PSZ = 1 << PB;
    constexpr bool USE_PLDS = (PSZ <= 2048);
    __shared__ float accx[PSZ];
    __shared__ float accy[PSZ];
    __shared__ float2 plds[USE_PLDS ? PSZ : 1];
    __shared__ unsigned int cnts[K3GRID];

    int p = blockIdx.x;
    int base = p << PB;
    for (int i = threadIdx.x; i < PSZ; i += blockDim.x) {
        accx[i] = 0.0f; accy[i] = 0.0f;
        if (USE_PLDS) {
            int g = base + i;
            plds[i] = (g < n) ? pred[g] : make_float2(0.0f, 0.0f);
        }
    }
    for (int b = threadIdx.x; b < K3GRID; b += blockDim.x)
        cnts[b] = gcnt[(size_t)b * nbins + p];
    __syncthreads();

    float es0 = estd[0] + EPSF, es1 = estd[1] + EPSF;
    float em0 = emean[0], em1 = emean[1];

    const int slots = K3GRID * CAP;
    for (int f = threadIdx.x; f < slots; f += blockDim.x) {
        int b = f / CAP;          // CAP is compile-time -> strength-reduced
        int t = f - b * CAP;
        if ((unsigned)t < cnts[b]) {
            unsigned long long rec = bkt[((size_t)b * nbins + p) * CAP + t];
            int e   = (int)(rec & 0x3FFFFFu);
            int o   = (int)((rec >> 22) & 0xFFFFFu);
            int lid = (int)(rec >> 42);
            float2 at = ea[e];
            float2 po = pred[o];
            float2 ps = USE_PLDS ? plds[lid] : pred[base + lid];
            float P, Q;
            msg_compute(ps, po, at, es0, es1, em0, em1, P, Q);
            atomicAdd(&accx[lid], P);
            atomicAdd(&accy[lid], Q);
        }
    }
    __syncthreads();

    float xs0 = xystd[0] + EPSF, xs1 = xystd[1] + EPSF;
    float xm0 = xymean[0], xm1 = xymean[1];
    double s = 0.0;
    for (int i = threadIdx.x; i < PSZ; i += blockDim.x) {
        int g = base + i;
        if (g < n) {
            float4 t = ty[g];
            float vx = t.x * xs0 + xm0 + accx[i] + calc[2 * (size_t)g];
            float vy = t.y * xs1 + xm1 + accy[i] + calc[2 * (size_t)g + 1];
            s += (double)vx * (double)vx + (double)vy * (double)vy;
        }
    }
    s = blockReduceSum(s);
    if (threadIdx.x == 0) atomicAdd(&sc->phys_sum, s);
}

// ---------------- fallback path: direct atomics ----------------

__global__ void pass2_edges(const int*    __restrict__ ei,
                            const float2* __restrict__ ea,
                            const float2* __restrict__ pred,
                            const float*  __restrict__ emean,
                            const float*  __restrict__ estd,
                            float*        __restrict__ calc,
                            int nE)
{
    float es0 = estd[0] + EPSF, es1 = estd[1] + EPSF;
    float em0 = emean[0], em1 = emean[1];
    int stride = gridDim.x * blockDim.x;
    for (int k = blockIdx.x * blockDim.x + threadIdx.x; k < nE; k += stride) {
        int a = ei[k];
        int b = ei[nE + k];
        float2 at = ea[k];
        float2 pa = pred[a];
        float2 pb = pred[b];
        float Pa, Qa, Pb, Qb;
        msg_compute(pa, pb, at, es0, es1, em0, em1, Pa, Qa);
        msg_compute(pb, pa, at, es0, es1, em0, em1, Pb, Qb);
        unsafeAtomicAdd(&calc[2 * (size_t)a],     Pa);
        unsafeAtomicAdd(&calc[2 * (size_t)a + 1], Qa);
        unsafeAtomicAdd(&calc[2 * (size_t)b],     Pb);
        unsafeAtomicAdd(&calc[2 * (size_t)b + 1], Qb);
    }
}

__global__ void pass3_phys(const float2* __restrict__ calc, Scalars* sc, int n)
{
    double s = 0.0;
    int stride = gridDim.x * blockDim.x;
    for (int i = blockIdx.x * blockDim.x + threadIdx.x; i < n; i += stride) {
        float2 c = calc[i];
        s += (double)c.x * (double)c.x + (double)c.y * (double)c.y;
    }
    s = blockReduceSum(s);
    if (threadIdx.x == 0) atomicAdd(&sc->phys_sum, s);
}

__global__ void finalize_kernel(const Scalars* __restrict__ sc, float* __restrict__ out, int n)
{
    if (threadIdx.x == 0 && blockIdx.x == 0) {
        double mse  = sc->mse_num / (sc->mse_den + 1e-6);
        double phys = sc->phys_sum / (2.0 * (double)n);
        double pv   = (sc->pv_cnt > 0.0) ? (sc->pv_sum / fmax(sc->pv_cnt, 1.0)) : 0.0;
        double total = 0.8 * mse + 0.2 * phys + 0.1 * pv;
        out[0] = (float)total;
        out[1] = (float)mse;
        out[2] = (float)phys;
        out[3] = (float)pv;
    }
}

extern "C" void kernel_launch(void* const* d_in, const int* in_sizes, int n_in,
                              void* d_out, int out_size, void* d_ws, size_t ws_size,
                              hipStream_t stream) {
    const float2* pred   = (const float2*)d_in[0];
    const float4* ty     = (const float4*)d_in[1];
    const float4* mask   = (const float4*)d_in[2];
    const int*    ei     = (const int*)d_in[3];
    const float2* ea     = (const float2*)d_in[4];
    const int*    bus    = (const int*)d_in[5];
    const float*  tvm    = (const float*)d_in[6];
    const float*  xymean = (const float*)d_in[7];
    const float*  xystd  = (const float*)d_in[8];
    const float*  emean  = (const float*)d_in[9];
    const float*  estd   = (const float*)d_in[10];
    float* out = (float*)d_out;

    int n  = in_sizes[0] / 2;   // nodes
    int nE = in_sizes[3] / 2;   // edges

    bool fits_pack = (n <= (1 << 20)) && (nE <= (1 << 22));

    char* basep = (char*)d_ws;
    Scalars* sc = (Scalars*)basep;
    size_t head = 64;
    float* calc = (float*)(basep + head);
    head += (size_t)2 * n * sizeof(float);
    head = (head + 7) & ~(size_t)7;

    // tier A: PB=11, CAP=64 ; tier B: PB=12, CAP=96
    int nbins11 = (n + 2047) >> 11;
    int nbins12 = (n + 4095) >> 12;
    size_t needA = head + (size_t)K3GRID * nbins11 * 4 + 8 +
                   (size_t)K3GRID * nbins11 * 64 * 8;
    size_t needB = head + (size_t)K3GRID * nbins12 * 4 + 8 +
                   (size_t)K3GRID * nbins12 * 96 * 8;

    const int BLK = 256, GRID = 2048;
    int tier = 2; // C
    if (fits_pack && nbins11 <= MAXBINS && needA <= ws_size) tier = 0;
    else if (fits_pack && nbins12 <= MAXBINS && needB <= ws_size) tier = 1;

    zero_scalars_kernel<<<1, 64, 0, stream>>>((double*)sc);

    if (tier == 0 || tier == 1) {
        int pb    = (tier == 0) ? 11 : 12;
        int cap   = (tier == 0) ? 64 : 96;
        int nbins = (tier == 0) ? nbins11 : nbins12;

        size_t off = head;
        unsigned int* gcnt = (unsigned int*)(basep + off);
        off += (size_t)K3GRID * nbins * sizeof(unsigned int);
        off = (off + 7) & ~(size_t)7;
        unsigned long long* bkt = (unsigned long long*)(basep + off);

        pass1_nodes<<<GRID, BLK, 0, stream>>>(pred, ty, mask, bus, tvm, xymean, xystd,
                                              (float2*)calc, sc, n, /*seed=*/0);
        scatter_idx<<<K3GRID, K3BLK, 0, stream>>>(ei, ea, pred, emean, estd,
                                                  bkt, gcnt, calc, nE, nbins, cap, pb);
        if (tier == 0)
            gather_t<11, 64><<<nbins, K4BLK, 0, stream>>>(bkt, gcnt, pred, ea, emean, estd,
                                                          calc, ty, xymean, xystd, sc, n, nbins);
        else
            gather_t<12, 96><<<nbins, K4BLK, 0, stream>>>(bkt, gcnt, pred, ea, emean, estd,
                                                          calc, ty, xymean, xystd, sc, n, nbins);
        finalize_kernel<<<1, 64, 0, stream>>>(sc, out, n);
    } else {
        pass1_nodes<<<GRID, BLK, 0, stream>>>(pred, ty, mask, bus, tvm, xymean, xystd,
                                              (float2*)calc, sc, n, /*seed=*/1);
        pass2_edges<<<GRID, BLK, 0, stream>>>(ei, ea, pred, emean, estd, calc, nE);
        pass3_phys<<<GRID, BLK, 0, stream>>>((const float2*)calc, sc, n);
        finalize_kernel<<<1, 64, 0, stream>>>(sc, out, n);
    }
}

// Round 5
// 320.626 us; speedup vs baseline: 2.8905x; 1.1188x over previous
//
#include <hip/hip_runtime.h>
#include <math.h>

#define EPSF 1e-7f

#define K3GRID  512        // scatter blocks (bucket dimension)
#define K3BLK   1024       // 512*16 waves = 8192 = 100% of wave slots
#define K4BLK   1024
#define MAXBINS 512        // static LDS counter bound in scatter

// new fast path: 2048-node partitions, 16B records with inlined edge attr
#define PB_NEW  11
#define PSZ_NEW (1 << PB_NEW)
#define CAPN_MIN 44        // mean fill 32 at K3GRID=512 -> 1.37x headroom

struct Scalars { double mse_num, mse_den, pv_sum, pv_cnt, phys_sum; };

typedef float f2v __attribute__((ext_vector_type(2)));
typedef float f4v __attribute__((ext_vector_type(4)));

__device__ __forceinline__ float2 nt_ld_f2(const float2* p) {
    f2v v = __builtin_nontemporal_load((const f2v*)p);
    return make_float2(v.x, v.y);
}
__device__ __forceinline__ float4 nt_ld_f4(const float4* p) {
    f4v v = __builtin_nontemporal_load((const f4v*)p);
    return make_float4(v.x, v.y, v.z, v.w);
}
__device__ __forceinline__ int nt_ld_i(const int* p) {
    return __builtin_nontemporal_load(p);
}
__device__ __forceinline__ float nt_ld_f(const float* p) {
    return __builtin_nontemporal_load(p);
}

__global__ void zero_scalars_kernel(double* s) {
    int i = threadIdx.x;
    if (i < 5) s[i] = 0.0;
}

// Block-wide sum reduction (valid on thread 0). blockDim.x <= 1024, mult of 64.
__device__ double blockReduceSum(double v) {
    __shared__ double red[16];
    #pragma unroll
    for (int off = 32; off > 0; off >>= 1)
        v += __shfl_down(v, off, 64);
    int lane = threadIdx.x & 63;
    int wid  = threadIdx.x >> 6;
    __syncthreads();
    if (lane == 0) red[wid] = v;
    __syncthreads();
    if (threadIdx.x == 0) {
        double s = 0.0;
        int nw = blockDim.x >> 6;
        for (int w = 0; w < nw; ++w) s += red[w];
        v = s;
    }
    return v;
}

// Pass 1: per-node — MSE terms, PV terms; writes calc = real_pq (seed=1) or zeros (seed=0).
__global__ void pass1_nodes(const float2* __restrict__ pred,
                            const float4* __restrict__ ty,
                            const float4* __restrict__ mask,
                            const int*    __restrict__ bus,
                            const float*  __restrict__ tvm,
                            const float*  __restrict__ xymean,
                            const float*  __restrict__ xystd,
                            float2*       __restrict__ calc,
                            Scalars* sc, int n, int seed_calc)
{
    float xs0 = xystd[0] + EPSF, xs1 = xystd[1] + EPSF;
    float xs2 = xystd[2] + EPSF, xs3 = xystd[3] + EPSF;
    float xm0 = xymean[0], xm1 = xymean[1], xm2 = xymean[2], xm3 = xymean[3];

    double mse_num = 0.0, mse_den = 0.0, pv_sum = 0.0, pv_cnt = 0.0;
    int stride = gridDim.x * blockDim.x;
    for (int i = blockIdx.x * blockDim.x + threadIdx.x; i < n; i += stride) {
        float2 p = pred[i];
        float4 t = nt_ld_f4(&ty[i]);
        float4 m = nt_ld_f4(&mask[i]);
        float d0 = p.x - t.z, d1 = p.y - t.w;
        mse_num += (double)(d0 * d0 * m.z + d1 * d1 * m.w);
        mse_den += (double)(m.z + m.w);
        calc[i] = seed_calc ? make_float2(t.x * xs0 + xm0, t.y * xs1 + xm1)
                            : make_float2(0.0f, 0.0f);
        float er0 = p.x * xs2 + xm2;
        float er1 = p.y * xs3 + xm3;
        float vmsq = er0 * er0 + er1 * er1;
        if (nt_ld_i(&bus[i]) == 1) {
            float tv = nt_ld_f(&tvm[i]);
            pv_sum += (double)fabsf(vmsq - tv * tv);
            pv_cnt += 1.0;
        }
    }
    mse_num = blockReduceSum(mse_num);
    mse_den = blockReduceSum(mse_den);
    pv_sum  = blockReduceSum(pv_sum);
    pv_cnt  = blockReduceSum(pv_cnt);
    if (threadIdx.x == 0) {
        atomicAdd(&sc->mse_num, mse_num);
        atomicAdd(&sc->mse_den, mse_den);
        atomicAdd(&sc->pv_sum,  pv_sum);
        atomicAdd(&sc->pv_cnt,  pv_cnt);
    }
}

__device__ __forceinline__ void msg_compute(float2 ps, float2 po, float2 at,
                                            float es0, float es1, float em0, float em1,
                                            float& P, float& Q)
{
    float g  = at.x * es0 + em0;
    float bb = at.y * es1 + em1;
    float t1 = ps.x * po.x + ps.y * po.y;
    float t2 = ps.y * po.x - ps.x * po.y;
    float vs = ps.x * ps.x + ps.y * ps.y;
    P =  g  * (vs - t1) - bb * t2;
    Q = -bb * (vs - t1) - g  * t2;
}

// ---------------- NEW fast path: 16B records with inlined g,b ----------------
// Record float4: x = bits(lid<<20 | other), y = g, z = b, w = unused.
// Requires n <= 2^20.

__global__ __launch_bounds__(K3BLK)
void scatter_gb(const int*    __restrict__ ei,    // (2, E)
                const float2* __restrict__ ea,
                const float2* __restrict__ pred,
                const float*  __restrict__ emean,
                const float*  __restrict__ estd,
                float4*       __restrict__ bkt,
                unsigned int* __restrict__ gcnt,   // [K3GRID][nbins]
                float*        __restrict__ calc,   // overflow accumulator
                int nE, int nbins, int cap)
{
    __shared__ unsigned int lcnt[MAXBINS];
    for (int i = threadIdx.x; i < nbins; i += blockDim.x) lcnt[i] = 0;
    __syncthreads();

    float es0 = estd[0] + EPSF, es1 = estd[1] + EPSF;
    float em0 = emean[0], em1 = emean[1];

    int tid = blockIdx.x * blockDim.x + threadIdx.x;
    int stride = gridDim.x * blockDim.x;
    for (int k = tid; k < nE; k += stride) {
        int a = nt_ld_i(&ei[k]);
        int b = nt_ld_i(&ei[nE + k]);
        float2 at = nt_ld_f2(&ea[k]);
        float g  = at.x * es0 + em0;
        float bb = at.y * es1 + em1;
        #pragma unroll
        for (int d = 0; d < 2; ++d) {
            int self  = d ? b : a;
            int other = d ? a : b;
            int bin = self >> PB_NEW;
            unsigned r = atomicAdd(&lcnt[bin], 1u);
            if (r < (unsigned)cap) {
                float4 rec;
                rec.x = __uint_as_float(((unsigned)(self & (PSZ_NEW - 1)) << 20) |
                                        (unsigned)other);
                rec.y = g; rec.z = bb; rec.w = 0.0f;
                bkt[((size_t)blockIdx.x * nbins + bin) * cap + r] = rec;
            } else {
                float2 ps = pred[self];
                float2 po = pred[other];
                float t1 = ps.x * po.x + ps.y * po.y;
                float t2 = ps.y * po.x - ps.x * po.y;
                float vs = ps.x * ps.x + ps.y * ps.y;
                float P =  g  * (vs - t1) - bb * t2;
                float Q = -bb * (vs - t1) - g  * t2;
                unsafeAtomicAdd(&calc[2 * (size_t)self],     P);
                unsafeAtomicAdd(&calc[2 * (size_t)self + 1], Q);
            }
        }
    }
    __syncthreads();
    for (int i = threadIdx.x; i < nbins; i += blockDim.x)
        gcnt[(size_t)blockIdx.x * nbins + i] = min(lcnt[i], (unsigned)cap);
}

// Gather: one block per 2048-node partition; wave-per-bucket (cap <= 64 -> one
// coalesced <=1KB read per bucket); self-pred from LDS; other-pred from cache.
__global__ __launch_bounds__(K4BLK)
void gather_gb(const float4*       __restrict__ bkt,
               const unsigned int* __restrict__ gcnt,
               const float2* __restrict__ pred,
               const float*  __restrict__ calc,   // overflow
               const float4* __restrict__ ty,
               const float*  __restrict__ xymean,
               const float*  __restrict__ xystd,
               Scalars* sc, int n, int nbins, int cap)
{
    __shared__ float accx[PSZ_NEW];
    __shared__ float accy[PSZ_NEW];
    __shared__ float2 plds[PSZ_NEW];
    __shared__ unsigned int cnts[K3GRID];

    int p = blockIdx.x;
    int base = p << PB_NEW;
    for (int i = threadIdx.x; i < PSZ_NEW; i += blockDim.x) {
        accx[i] = 0.0f; accy[i] = 0.0f;
        int g = base + i;
        plds[i] = (g < n) ? pred[g] : make_float2(0.0f, 0.0f);
    }
    for (int b = threadIdx.x; b < K3GRID; b += blockDim.x)
        cnts[b] = gcnt[(size_t)b * nbins + p];
    __syncthreads();

    int lane = threadIdx.x & 63;
    int wid  = threadIdx.x >> 6;
    int nw   = blockDim.x >> 6;
    for (int b = wid; b < K3GRID; b += nw) {
        unsigned c = cnts[b];
        if ((unsigned)lane < c) {
            float4 rec = nt_ld_f4(&bkt[((size_t)b * nbins + p) * cap + lane]);
            unsigned meta = __float_as_uint(rec.x);
            int o   = (int)(meta & 0xFFFFFu);
            int lid = (int)(meta >> 20);
            float g  = rec.y;
            float bb = rec.z;
            float2 po = pred[o];
            float2 ps = plds[lid];
            float t1 = ps.x * po.x + ps.y * po.y;
            float t2 = ps.y * po.x - ps.x * po.y;
            float vs = ps.x * ps.x + ps.y * ps.y;
            float P =  g  * (vs - t1) - bb * t2;
            float Q = -bb * (vs - t1) - g  * t2;
            atomicAdd(&accx[lid], P);
            atomicAdd(&accy[lid], Q);
        }
    }
    __syncthreads();

    float xs0 = xystd[0] + EPSF, xs1 = xystd[1] + EPSF;
    float xm0 = xymean[0], xm1 = xymean[1];
    double s = 0.0;
    for (int i = threadIdx.x; i < PSZ_NEW; i += blockDim.x) {
        int g = base + i;
        if (g < n) {
            float4 t = nt_ld_f4(&ty[g]);
            float vx = t.x * xs0 + xm0 + accx[i] + calc[2 * (size_t)g];
            float vy = t.y * xs1 + xm1 + accy[i] + calc[2 * (size_t)g + 1];
            s += (double)vx * (double)vx + (double)vy * (double)vy;
        }
    }
    s = blockReduceSum(s);
    if (threadIdx.x == 0) atomicAdd(&sc->phys_sum, s);
}

// ---------------- OLD fast path (R4): 8B index records ----------------
// Record: [lid:12][other:20][edge:22]  (requires n <= 2^20, nE <= 2^22)

__global__ __launch_bounds__(K3BLK)
void scatter_idx(const int*    __restrict__ ei,
                 const float2* __restrict__ ea,
                 const float2* __restrict__ pred,
                 const float*  __restrict__ emean,
                 const float*  __restrict__ estd,
                 unsigned long long* __restrict__ bkt,
                 unsigned int*       __restrict__ gcnt,
                 float*              __restrict__ calc,
                 int nE, int nbins, int cap, int part_bits)
{
    __shared__ unsigned int lcnt[MAXBINS];
    for (int i = threadIdx.x; i < nbins; i += blockDim.x) lcnt[i] = 0;
    __syncthreads();

    float es0 = estd[0] + EPSF, es1 = estd[1] + EPSF;
    float em0 = emean[0], em1 = emean[1];
    unsigned lmask = (1u << part_bits) - 1u;

    int tid = blockIdx.x * blockDim.x + threadIdx.x;
    int stride = gridDim.x * blockDim.x;
    for (int k = tid; k < nE; k += stride) {
        int a = nt_ld_i(&ei[k]);
        int b = nt_ld_i(&ei[nE + k]);
        #pragma unroll
        for (int d = 0; d < 2; ++d) {
            int self  = d ? b : a;
            int other = d ? a : b;
            int bin = self >> part_bits;
            unsigned r = atomicAdd(&lcnt[bin], 1u);
            if (r < (unsigned)cap) {
                unsigned long long rec =
                    ((unsigned long long)((unsigned)self & lmask) << 42) |
                    ((unsigned long long)(unsigned)other << 22) |
                    (unsigned long long)(unsigned)k;
                bkt[((size_t)blockIdx.x * nbins + bin) * cap + r] = rec;
            } else {
                float2 ps = pred[self];
                float2 po = pred[other];
                float2 at = ea[k];
                float P, Q;
                msg_compute(ps, po, at, es0, es1, em0, em1, P, Q);
                unsafeAtomicAdd(&calc[2 * (size_t)self],     P);
                unsafeAtomicAdd(&calc[2 * (size_t)self + 1], Q);
            }
        }
    }
    __syncthreads();
    for (int i = threadIdx.x; i < nbins; i += blockDim.x)
        gcnt[(size_t)blockIdx.x * nbins + i] = min(lcnt[i], (unsigned)cap);
}

template<int PB, int CAP>
__global__ __launch_bounds__(K4BLK)
void gather_t(const unsigned long long* __restrict__ bkt,
              const unsigned int*       __restrict__ gcnt,
              const float2* __restrict__ pred,
              const float2* __restrict__ ea,
              const float*  __restrict__ emean,
              const float*  __restrict__ estd,
              const float*  __restrict__ calc,
              const float4* __restrict__ ty,
              const float*  __restrict__ xymean,
              const float*  __restrict__ xystd,
              Scalars* sc, int n, int nbins)
{
    constexpr int PSZ = 1 << PB;
    constexpr bool USE_PLDS = (PSZ <= 2048);
    __shared__ float accx[PSZ];
    __shared__ float accy[PSZ];
    __shared__ float2 plds[USE_PLDS ? PSZ : 1];
    __shared__ unsigned int cnts[K3GRID];

    int p = blockIdx.x;
    int base = p << PB;
    for (int i = threadIdx.x; i < PSZ; i += blockDim.x) {
        accx[i] = 0.0f; accy[i] = 0.0f;
        if (USE_PLDS) {
            int g = base + i;
            plds[i] = (g < n) ? pred[g] : make_float2(0.0f, 0.0f);
        }
    }
    for (int b = threadIdx.x; b < K3GRID; b += blockDim.x)
        cnts[b] = gcnt[(size_t)b * nbins + p];
    __syncthreads();

    float es0 = estd[0] + EPSF, es1 = estd[1] + EPSF;
    float em0 = emean[0], em1 = emean[1];

    const int slots = K3GRID * CAP;
    for (int f = threadIdx.x; f < slots; f += blockDim.x) {
        int b = f / CAP;
        int t = f - b * CAP;
        if ((unsigned)t < cnts[b]) {
            unsigned long long rec = bkt[((size_t)b * nbins + p) * CAP + t];
            int e   = (int)(rec & 0x3FFFFFu);
            int o   = (int)((rec >> 22) & 0xFFFFFu);
            int lid = (int)(rec >> 42);
            float2 at = ea[e];
            float2 po = pred[o];
            float2 ps = USE_PLDS ? plds[lid] : pred[base + lid];
            float P, Q;
            msg_compute(ps, po, at, es0, es1, em0, em1, P, Q);
            atomicAdd(&accx[lid], P);
            atomicAdd(&accy[lid], Q);
        }
    }
    __syncthreads();

    float xs0 = xystd[0] + EPSF, xs1 = xystd[1] + EPSF;
    float xm0 = xymean[0], xm1 = xymean[1];
    double s = 0.0;
    for (int i = threadIdx.x; i < PSZ; i += blockDim.x) {
        int g = base + i;
        if (g < n) {
            float4 t = ty[g];
            float vx = t.x * xs0 + xm0 + accx[i] + calc[2 * (size_t)g];
            float vy = t.y * xs1 + xm1 + accy[i] + calc[2 * (size_t)g + 1];
            s += (double)vx * (double)vx + (double)vy * (double)vy;
        }
    }
    s = blockReduceSum(s);
    if (threadIdx.x == 0) atomicAdd(&sc->phys_sum, s);
}

// ---------------- fallback path: direct atomics ----------------

__global__ void pass2_edges(const int*    __restrict__ ei,
                            const float2* __restrict__ ea,
                            const float2* __restrict__ pred,
                            const float*  __restrict__ emean,
                            const float*  __restrict__ estd,
                            float*        __restrict__ calc,
                            int nE)
{
    float es0 = estd[0] + EPSF, es1 = estd[1] + EPSF;
    float em0 = emean[0], em1 = emean[1];
    int stride = gridDim.x * blockDim.x;
    for (int k = blockIdx.x * blockDim.x + threadIdx.x; k < nE; k += stride) {
        int a = ei[k];
        int b = ei[nE + k];
        float2 at = ea[k];
        float2 pa = pred[a];
        float2 pb = pred[b];
        float Pa, Qa, Pb, Qb;
        msg_compute(pa, pb, at, es0, es1, em0, em1, Pa, Qa);
        msg_compute(pb, pa, at, es0, es1, em0, em1, Pb, Qb);
        unsafeAtomicAdd(&calc[2 * (size_t)a],     Pa);
        unsafeAtomicAdd(&calc[2 * (size_t)a + 1], Qa);
        unsafeAtomicAdd(&calc[2 * (size_t)b],     Pb);
        unsafeAtomicAdd(&calc[2 * (size_t)b + 1], Qb);
    }
}

__global__ void pass3_phys(const float2* __restrict__ calc, Scalars* sc, int n)
{
    double s = 0.0;
    int stride = gridDim.x * blockDim.x;
    for (int i = blockIdx.x * blockDim.x + threadIdx.x; i < n; i += stride) {
        float2 c = calc[i];
        s += (double)c.x * (double)c.x + (double)c.y * (double)c.y;
    }
    s = blockReduceSum(s);
    if (threadIdx.x == 0) atomicAdd(&sc->phys_sum, s);
}

__global__ void finalize_kernel(const Scalars* __restrict__ sc, float* __restrict__ out, int n)
{
    if (threadIdx.x == 0 && blockIdx.x == 0) {
        double mse  = sc->mse_num / (sc->mse_den + 1e-6);
        double phys = sc->phys_sum / (2.0 * (double)n);
        double pv   = (sc->pv_cnt > 0.0) ? (sc->pv_sum / fmax(sc->pv_cnt, 1.0)) : 0.0;
        double total = 0.8 * mse + 0.2 * phys + 0.1 * pv;
        out[0] = (float)total;
        out[1] = (float)mse;
        out[2] = (float)phys;
        out[3] = (float)pv;
    }
}

extern "C" void kernel_launch(void* const* d_in, const int* in_sizes, int n_in,
                              void* d_out, int out_size, void* d_ws, size_t ws_size,
                              hipStream_t stream) {
    const float2* pred   = (const float2*)d_in[0];
    const float4* ty     = (const float4*)d_in[1];
    const float4* mask   = (const float4*)d_in[2];
    const int*    ei     = (const int*)d_in[3];
    const float2* ea     = (const float2*)d_in[4];
    const int*    bus    = (const int*)d_in[5];
    const float*  tvm    = (const float*)d_in[6];
    const float*  xymean = (const float*)d_in[7];
    const float*  xystd  = (const float*)d_in[8];
    const float*  emean  = (const float*)d_in[9];
    const float*  estd   = (const float*)d_in[10];
    float* out = (float*)d_out;

    int n  = in_sizes[0] / 2;   // nodes
    int nE = in_sizes[3] / 2;   // edges

    char* basep = (char*)d_ws;
    Scalars* sc = (Scalars*)basep;
    size_t head = 64;
    float* calc = (float*)(basep + head);
    head += (size_t)2 * n * sizeof(float);
    head = (head + 15) & ~(size_t)15;

    const int BLK = 256, GRID = 2048;

    // ---- NEW tier: PB=11, 16B records, adaptive cap up to 64 ----
    int nbinsN = (n + PSZ_NEW - 1) >> PB_NEW;
    size_t slotsN = (size_t)K3GRID * nbinsN;
    size_t offN = head + slotsN * sizeof(unsigned int);
    offN = (offN + 15) & ~(size_t)15;
    int capN = 0;
    if (ws_size > offN)
        capN = (int)((ws_size - offN) / (slotsN * sizeof(float4)));
    if (capN > 64) capN = 64;
    bool useNew = (n <= (1 << 20)) && (nbinsN <= MAXBINS) && (capN >= CAPN_MIN);

    zero_scalars_kernel<<<1, 64, 0, stream>>>((double*)sc);

    if (useNew) {
        unsigned int* gcnt = (unsigned int*)(basep + head);
        float4* bkt = (float4*)(basep + offN);

        pass1_nodes<<<GRID, BLK, 0, stream>>>(pred, ty, mask, bus, tvm, xymean, xystd,
                                              (float2*)calc, sc, n, /*seed=*/0);
        scatter_gb<<<K3GRID, K3BLK, 0, stream>>>(ei, ea, pred, emean, estd,
                                                 bkt, gcnt, calc, nE, nbinsN, capN);
        gather_gb<<<nbinsN, K4BLK, 0, stream>>>(bkt, gcnt, pred, calc, ty,
                                                xymean, xystd, sc, n, nbinsN, capN);
        finalize_kernel<<<1, 64, 0, stream>>>(sc, out, n);
        return;
    }

    // ---- OLD tiers: 8B records ----
    bool fits_pack = (n <= (1 << 20)) && (nE <= (1 << 22));
    int nbins11 = (n + 2047) >> 11;
    int nbins12 = (n + 4095) >> 12;
    size_t needA = head + (size_t)K3GRID * nbins11 * 4 + 16 +
                   (size_t)K3GRID * nbins11 * 64 * 8;
    size_t needB = head + (size_t)K3GRID * nbins12 * 4 + 16 +
                   (size_t)K3GRID * nbins12 * 96 * 8;

    int tier = 2;
    if (fits_pack && nbins11 <= MAXBINS && needA <= ws_size) tier = 0;
    else if (fits_pack && nbins12 <= MAXBINS && needB <= ws_size) tier = 1;

    if (tier == 0 || tier == 1) {
        int pb    = (tier == 0) ? 11 : 12;
        int cap   = (tier == 0) ? 64 : 96;
        int nbins = (tier == 0) ? nbins11 : nbins12;

        size_t off = head;
        unsigned int* gcnt = (unsigned int*)(basep + off);
        off += (size_t)K3GRID * nbins * sizeof(unsigned int);
        off = (off + 15) & ~(size_t)15;
        unsigned long long* bkt = (unsigned long long*)(basep + off);

        pass1_nodes<<<GRID, BLK, 0, stream>>>(pred, ty, mask, bus, tvm, xymean, xystd,
                                              (float2*)calc, sc, n, /*seed=*/0);
        scatter_idx<<<K3GRID, K3BLK, 0, stream>>>(ei, ea, pred, emean, estd,
                                                  bkt, gcnt, calc, nE, nbins, cap, pb);
        if (tier == 0)
            gather_t<11, 64><<<nbins, K4BLK, 0, stream>>>(bkt, gcnt, pred, ea, emean, estd,
                                                          calc, ty, xymean, xystd, sc, n, nbins);
        else
            gather_t<12, 96><<<nbins, K4BLK, 0, stream>>>(bkt, gcnt, pred, ea, emean, estd,
                                                          calc, ty, xymean, xystd, sc, n, nbins);
        finalize_kernel<<<1, 64, 0, stream>>>(sc, out, n);
    } else {
        pass1_nodes<<<GRID, BLK, 0, stream>>>(pred, ty, mask, bus, tvm, xymean, xystd,
                                              (float2*)calc, sc, n, /*seed=*/1);
        pass2_edges<<<GRID, BLK, 0, stream>>>(ei, ea, pred, emean, estd, calc, nE);
        pass3_phys<<<GRID, BLK, 0, stream>>>((const float2*)calc, sc, n);
        finalize_kernel<<<1, 64, 0, stream>>>(sc, out, n);
    }
}

// Round 6
// 224.476 us; speedup vs baseline: 4.1286x; 1.4283x over previous
//
#include <hip/hip_runtime.h>
#include <math.h>

#define EPSF 1e-7f

#define K3GRID  512        // scatter blocks (bucket dimension)
#define K3BLK   1024       // 512*16 waves = 8192 = 100% of wave slots
#define K4BLK   1024
#define MAXBINS 512        // static LDS counter bound in scatter

// fast path: 2048-node partitions, 16B records {meta, g, b, pad}, cap 44
#define PB_NEW  11
#define PSZ_NEW (1 << PB_NEW)
#define CAPF    44

struct Scalars { double mse_num, mse_den, pv_sum, pv_cnt, phys_sum; };

typedef float f2v __attribute__((ext_vector_type(2)));
typedef float f4v __attribute__((ext_vector_type(4)));
typedef int   i2v __attribute__((ext_vector_type(2)));

__device__ __forceinline__ float2 nt_ld_f2(const float2* p) {
    f2v v = __builtin_nontemporal_load((const f2v*)p);
    return make_float2(v.x, v.y);
}
__device__ __forceinline__ float4 nt_ld_f4(const float4* p) {
    f4v v = __builtin_nontemporal_load((const f4v*)p);
    return make_float4(v.x, v.y, v.z, v.w);
}
__device__ __forceinline__ int2 nt_ld_i2(const int2* p) {
    i2v v = __builtin_nontemporal_load((const i2v*)p);
    return make_int2(v.x, v.y);
}
__device__ __forceinline__ int nt_ld_i(const int* p) {
    return __builtin_nontemporal_load(p);
}
__device__ __forceinline__ float nt_ld_f(const float* p) {
    return __builtin_nontemporal_load(p);
}

__global__ void zero_scalars_kernel(double* s) {
    int i = threadIdx.x;
    if (i < 5) s[i] = 0.0;
}

__global__ void zero_f32_kernel(float* p, int n) {
    int stride = gridDim.x * blockDim.x;
    for (int i = blockIdx.x * blockDim.x + threadIdx.x; i < n; i += stride)
        p[i] = 0.0f;
}

// Block-wide sum reduction (valid on thread 0). blockDim.x <= 1024, mult of 64.
__device__ double blockReduceSum(double v) {
    __shared__ double red[16];
    #pragma unroll
    for (int off = 32; off > 0; off >>= 1)
        v += __shfl_down(v, off, 64);
    int lane = threadIdx.x & 63;
    int wid  = threadIdx.x >> 6;
    __syncthreads();
    if (lane == 0) red[wid] = v;
    __syncthreads();
    if (threadIdx.x == 0) {
        double s = 0.0;
        int nw = blockDim.x >> 6;
        for (int w = 0; w < nw; ++w) s += red[w];
        v = s;
    }
    return v;
}

__device__ __forceinline__ void msg_compute(float2 ps, float2 po, float2 at,
                                            float es0, float es1, float em0, float em1,
                                            float& P, float& Q)
{
    float g  = at.x * es0 + em0;
    float bb = at.y * es1 + em1;
    float t1 = ps.x * po.x + ps.y * po.y;
    float t2 = ps.y * po.x - ps.x * po.y;
    float vs = ps.x * ps.x + ps.y * ps.y;
    P =  g  * (vs - t1) - bb * t2;
    Q = -bb * (vs - t1) - g  * t2;
}

// Pass 1 (fallback tiers only)
__global__ void pass1_nodes(const float2* __restrict__ pred,
                            const float4* __restrict__ ty,
                            const float4* __restrict__ mask,
                            const int*    __restrict__ bus,
                            const float*  __restrict__ tvm,
                            const float*  __restrict__ xymean,
                            const float*  __restrict__ xystd,
                            float2*       __restrict__ calc,
                            Scalars* sc, int n, int seed_calc)
{
    float xs0 = xystd[0] + EPSF, xs1 = xystd[1] + EPSF;
    float xs2 = xystd[2] + EPSF, xs3 = xystd[3] + EPSF;
    float xm0 = xymean[0], xm1 = xymean[1], xm2 = xymean[2], xm3 = xymean[3];

    double mse_num = 0.0, mse_den = 0.0, pv_sum = 0.0, pv_cnt = 0.0;
    int stride = gridDim.x * blockDim.x;
    for (int i = blockIdx.x * blockDim.x + threadIdx.x; i < n; i += stride) {
        float2 p = pred[i];
        float4 t = nt_ld_f4(&ty[i]);
        float4 m = nt_ld_f4(&mask[i]);
        float d0 = p.x - t.z, d1 = p.y - t.w;
        mse_num += (double)(d0 * d0 * m.z + d1 * d1 * m.w);
        mse_den += (double)(m.z + m.w);
        calc[i] = seed_calc ? make_float2(t.x * xs0 + xm0, t.y * xs1 + xm1)
                            : make_float2(0.0f, 0.0f);
        float er0 = p.x * xs2 + xm2;
        float er1 = p.y * xs3 + xm3;
        float vmsq = er0 * er0 + er1 * er1;
        if (nt_ld_i(&bus[i]) == 1) {
            float tv = nt_ld_f(&tvm[i]);
            pv_sum += (double)fabsf(vmsq - tv * tv);
            pv_cnt += 1.0;
        }
    }
    mse_num = blockReduceSum(mse_num);
    mse_den = blockReduceSum(mse_den);
    pv_sum  = blockReduceSum(pv_sum);
    pv_cnt  = blockReduceSum(pv_cnt);
    if (threadIdx.x == 0) {
        atomicAdd(&sc->mse_num, mse_num);
        atomicAdd(&sc->mse_den, mse_den);
        atomicAdd(&sc->pv_sum,  pv_sum);
        atomicAdd(&sc->pv_cnt,  pv_cnt);
    }
}

// ---------------- fast path: scatter (paired edges) + fused gather ----------------
// Record float4: x = bits(lid<<20 | other), y = g, z = b, w = unused. n <= 2^20.

__global__ __launch_bounds__(K3BLK)
void scatter_gb2(const int*    __restrict__ ei,    // (2, E)
                 const float2* __restrict__ ea,
                 const float2* __restrict__ pred,
                 const float*  __restrict__ emean,
                 const float*  __restrict__ estd,
                 float4*       __restrict__ bkt,
                 unsigned int* __restrict__ gcnt,   // [K3GRID][nbins]
                 float*        __restrict__ calc,   // overflow accumulator
                 int nE, int nbins)
{
    __shared__ unsigned int lcnt[MAXBINS];
    for (int i = threadIdx.x; i < nbins; i += blockDim.x) lcnt[i] = 0;
    __syncthreads();

    float es0 = estd[0] + EPSF, es1 = estd[1] + EPSF;
    float em0 = emean[0], em1 = emean[1];

    int tid = blockIdx.x * blockDim.x + threadIdx.x;
    int stride = gridDim.x * blockDim.x;
    int npair = nE >> 1;

    #define EMIT(SELF, OTHER, G, B)                                              \
        do {                                                                     \
            int bin = (SELF) >> PB_NEW;                                          \
            unsigned r = atomicAdd(&lcnt[bin], 1u);                              \
            if (r < (unsigned)CAPF) {                                            \
                float4 rec;                                                      \
                rec.x = __uint_as_float(((unsigned)((SELF) & (PSZ_NEW - 1)) << 20) | \
                                        (unsigned)(OTHER));                      \
                rec.y = (G); rec.z = (B); rec.w = 0.0f;                          \
                bkt[((size_t)blockIdx.x * nbins + bin) * CAPF + r] = rec;        \
            } else {                                                             \
                float2 ps = pred[SELF];                                          \
                float2 po = pred[OTHER];                                         \
                float t1 = ps.x * po.x + ps.y * po.y;                            \
                float t2 = ps.y * po.x - ps.x * po.y;                            \
                float vs = ps.x * ps.x + ps.y * ps.y;                            \
                float P =  (G) * (vs - t1) - (B) * t2;                           \
                float Q = -(B) * (vs - t1) - (G) * t2;                           \
                unsafeAtomicAdd(&calc[2 * (size_t)(SELF)],     P);               \
                unsafeAtomicAdd(&calc[2 * (size_t)(SELF) + 1], Q);               \
            }                                                                    \
        } while (0)

    for (int q = tid; q < npair; q += stride) {
        int2 av = nt_ld_i2(&((const int2*)ei)[q]);
        int2 bv = nt_ld_i2(&((const int2*)(ei + nE))[q]);
        float4 e2 = nt_ld_f4(&((const float4*)ea)[q]);
        float g0 = e2.x * es0 + em0, b0 = e2.y * es1 + em1;
        float g1 = e2.z * es0 + em0, b1 = e2.w * es1 + em1;
        EMIT(av.x, bv.x, g0, b0);
        EMIT(bv.x, av.x, g0, b0);
        EMIT(av.y, bv.y, g1, b1);
        EMIT(bv.y, av.y, g1, b1);
    }
    if ((nE & 1) && tid == 0) {
        int k = nE - 1;
        int a = ei[k], b = ei[nE + k];
        float2 at = ea[k];
        float g = at.x * es0 + em0, bb = at.y * es1 + em1;
        EMIT(a, b, g, bb);
        EMIT(b, a, g, bb);
    }
    #undef EMIT

    __syncthreads();
    for (int i = threadIdx.x; i < nbins; i += blockDim.x)
        gcnt[(size_t)blockIdx.x * nbins + i] = min(lcnt[i], (unsigned)CAPF);
}

// Fused gather: message accumulation + MSE + PV + phys epilogue in one kernel.
__global__ __launch_bounds__(K4BLK)
void gather_fused(const float4*       __restrict__ bkt,
                  const unsigned int* __restrict__ gcnt,
                  const float2* __restrict__ pred,
                  const float*  __restrict__ calc,   // overflow
                  const float4* __restrict__ ty,
                  const float4* __restrict__ mask,
                  const int*    __restrict__ bus,
                  const float*  __restrict__ tvm,
                  const float*  __restrict__ xymean,
                  const float*  __restrict__ xystd,
                  Scalars* sc, int n, int nbins)
{
    __shared__ float accx[PSZ_NEW];
    __shared__ float accy[PSZ_NEW];
    __shared__ float2 plds[PSZ_NEW];
    __shared__ unsigned int cnts[K3GRID];

    int p = blockIdx.x;
    int base = p << PB_NEW;
    for (int i = threadIdx.x; i < PSZ_NEW; i += blockDim.x) {
        accx[i] = 0.0f; accy[i] = 0.0f;
        int g = base + i;
        plds[i] = (g < n) ? pred[g] : make_float2(0.0f, 0.0f);
    }
    for (int b = threadIdx.x; b < K3GRID; b += blockDim.x)
        cnts[b] = gcnt[(size_t)b * nbins + p];
    __syncthreads();

    // slot loop: compile-time CAPF -> strength-reduced div; ~73% lane fill
    const int slots = K3GRID * CAPF;
    for (int f = threadIdx.x; f < slots; f += blockDim.x) {
        int b = f / CAPF;
        int t = f - b * CAPF;
        if ((unsigned)t < cnts[b]) {
            float4 rec = nt_ld_f4(&bkt[((size_t)b * nbins + p) * CAPF + t]);
            unsigned meta = __float_as_uint(rec.x);
            int o   = (int)(meta & 0xFFFFFu);
            int lid = (int)(meta >> 20);
            float g  = rec.y;
            float bb = rec.z;
            float2 po = pred[o];
            float2 ps = plds[lid];
            float t1 = ps.x * po.x + ps.y * po.y;
            float t2 = ps.y * po.x - ps.x * po.y;
            float vs = ps.x * ps.x + ps.y * ps.y;
            float P =  g  * (vs - t1) - bb * t2;
            float Q = -bb * (vs - t1) - g  * t2;
            atomicAdd(&accx[lid], P);
            atomicAdd(&accy[lid], Q);
        }
    }
    __syncthreads();

    // epilogue: MSE + PV + phys for this partition's nodes
    float xs0 = xystd[0] + EPSF, xs1 = xystd[1] + EPSF;
    float xs2 = xystd[2] + EPSF, xs3 = xystd[3] + EPSF;
    float xm0 = xymean[0], xm1 = xymean[1], xm2 = xymean[2], xm3 = xymean[3];

    double mse_num = 0.0, mse_den = 0.0, pv_sum = 0.0, pv_cnt = 0.0, phys = 0.0;
    for (int i = threadIdx.x; i < PSZ_NEW; i += blockDim.x) {
        int g = base + i;
        if (g < n) {
            float2 pp = plds[i];
            float4 t = nt_ld_f4(&ty[g]);
            float4 m = nt_ld_f4(&mask[g]);
            float d0 = pp.x - t.z, d1 = pp.y - t.w;
            mse_num += (double)(d0 * d0 * m.z + d1 * d1 * m.w);
            mse_den += (double)(m.z + m.w);
            float er0 = pp.x * xs2 + xm2;
            float er1 = pp.y * xs3 + xm3;
            float vmsq = er0 * er0 + er1 * er1;
            if (nt_ld_i(&bus[g]) == 1) {
                float tv = nt_ld_f(&tvm[g]);
                pv_sum += (double)fabsf(vmsq - tv * tv);
                pv_cnt += 1.0;
            }
            float2 ov = ((const float2*)calc)[g];
            float vx = t.x * xs0 + xm0 + accx[i] + ov.x;
            float vy = t.y * xs1 + xm1 + accy[i] + ov.y;
            phys += (double)vx * (double)vx + (double)vy * (double)vy;
        }
    }
    mse_num = blockReduceSum(mse_num);
    mse_den = blockReduceSum(mse_den);
    pv_sum  = blockReduceSum(pv_sum);
    pv_cnt  = blockReduceSum(pv_cnt);
    phys    = blockReduceSum(phys);
    if (threadIdx.x == 0) {
        atomicAdd(&sc->mse_num, mse_num);
        atomicAdd(&sc->mse_den, mse_den);
        atomicAdd(&sc->pv_sum,  pv_sum);
        atomicAdd(&sc->pv_cnt,  pv_cnt);
        atomicAdd(&sc->phys_sum, phys);
    }
}

// ---------------- OLD fast path (R4): 8B index records (fallback tier) ----------------

__global__ __launch_bounds__(K3BLK)
void scatter_idx(const int*    __restrict__ ei,
                 const float2* __restrict__ ea,
                 const float2* __restrict__ pred,
                 const float*  __restrict__ emean,
                 const float*  __restrict__ estd,
                 unsigned long long* __restrict__ bkt,
                 unsigned int*       __restrict__ gcnt,
                 float*              __restrict__ calc,
                 int nE, int nbins, int cap, int part_bits)
{
    __shared__ unsigned int lcnt[MAXBINS];
    for (int i = threadIdx.x; i < nbins; i += blockDim.x) lcnt[i] = 0;
    __syncthreads();

    float es0 = estd[0] + EPSF, es1 = estd[1] + EPSF;
    float em0 = emean[0], em1 = emean[1];
    unsigned lmask = (1u << part_bits) - 1u;

    int tid = blockIdx.x * blockDim.x + threadIdx.x;
    int stride = gridDim.x * blockDim.x;
    for (int k = tid; k < nE; k += stride) {
        int a = nt_ld_i(&ei[k]);
        int b = nt_ld_i(&ei[nE + k]);
        #pragma unroll
        for (int d = 0; d < 2; ++d) {
            int self  = d ? b : a;
            int other = d ? a : b;
            int bin = self >> part_bits;
            unsigned r = atomicAdd(&lcnt[bin], 1u);
            if (r < (unsigned)cap) {
                unsigned long long rec =
                    ((unsigned long long)((unsigned)self & lmask) << 42) |
                    ((unsigned long long)(unsigned)other << 22) |
                    (unsigned long long)(unsigned)k;
                bkt[((size_t)blockIdx.x * nbins + bin) * cap + r] = rec;
            } else {
                float2 ps = pred[self];
                float2 po = pred[other];
                float2 at = ea[k];
                float P, Q;
                msg_compute(ps, po, at, es0, es1, em0, em1, P, Q);
                unsafeAtomicAdd(&calc[2 * (size_t)self],     P);
                unsafeAtomicAdd(&calc[2 * (size_t)self + 1], Q);
            }
        }
    }
    __syncthreads();
    for (int i = threadIdx.x; i < nbins; i += blockDim.x)
        gcnt[(size_t)blockIdx.x * nbins + i] = min(lcnt[i], (unsigned)cap);
}

template<int PB, int CAP>
__global__ __launch_bounds__(K4BLK)
void gather_t(const unsigned long long* __restrict__ bkt,
              const unsigned int*       __restrict__ gcnt,
              const float2* __restrict__ pred,
              const float2* __restrict__ ea,
              const float*  __restrict__ emean,
              const float*  __restrict__ estd,
              const float*  __restrict__ calc,
              const float4* __restrict__ ty,
              const float*  __restrict__ xymean,
              const float*  __restrict__ xystd,
              Scalars* sc, int n, int nbins)
{
    constexpr int PSZ = 1 << PB;
    constexpr bool USE_PLDS = (PSZ <= 2048);
    __shared__ float accx[PSZ];
    __shared__ float accy[PSZ];
    __shared__ float2 plds[USE_PLDS ? PSZ : 1];
    __shared__ unsigned int cnts[K3GRID];

    int p = blockIdx.x;
    int base = p << PB;
    for (int i = threadIdx.x; i < PSZ; i += blockDim.x) {
        accx[i] = 0.0f; accy[i] = 0.0f;
        if (USE_PLDS) {
            int g = base + i;
            plds[i] = (g < n) ? pred[g] : make_float2(0.0f, 0.0f);
        }
    }
    for (int b = threadIdx.x; b < K3GRID; b += blockDim.x)
        cnts[b] = gcnt[(size_t)b * nbins + p];
    __syncthreads();

    float es0 = estd[0] + EPSF, es1 = estd[1] + EPSF;
    float em0 = emean[0], em1 = emean[1];

    const int slots = K3GRID * CAP;
    for (int f = threadIdx.x; f < slots; f += blockDim.x) {
        int b = f / CAP;
        int t = f - b * CAP;
        if ((unsigned)t < cnts[b]) {
            unsigned long long rec = bkt[((size_t)b * nbins + p) * CAP + t];
            int e   = (int)(rec & 0x3FFFFFu);
            int o   = (int)((rec >> 22) & 0xFFFFFu);
            int lid = (int)(rec >> 42);
            float2 at = ea[e];
            float2 po = pred[o];
            float2 ps = USE_PLDS ? plds[lid] : pred[base + lid];
            float P, Q;
            msg_compute(ps, po, at, es0, es1, em0, em1, P, Q);
            atomicAdd(&accx[lid], P);
            atomicAdd(&accy[lid], Q);
        }
    }
    __syncthreads();

    float xs0 = xystd[0] + EPSF, xs1 = xystd[1] + EPSF;
    float xm0 = xymean[0], xm1 = xymean[1];
    double s = 0.0;
    for (int i = threadIdx.x; i < PSZ; i += blockDim.x) {
        int g = base + i;
        if (g < n) {
            float4 t = ty[g];
            float vx = t.x * xs0 + xm0 + accx[i] + calc[2 * (size_t)g];
            float vy = t.y * xs1 + xm1 + accy[i] + calc[2 * (size_t)g + 1];
            s += (double)vx * (double)vx + (double)vy * (double)vy;
        }
    }
    s = blockReduceSum(s);
    if (threadIdx.x == 0) atomicAdd(&sc->phys_sum, s);
}

// ---------------- fallback path: direct atomics ----------------

__global__ void pass2_edges(const int*    __restrict__ ei,
                            const float2* __restrict__ ea,
                            const float2* __restrict__ pred,
                            const float*  __restrict__ emean,
                            const float*  __restrict__ estd,
                            float*        __restrict__ calc,
                            int nE)
{
    float es0 = estd[0] + EPSF, es1 = estd[1] + EPSF;
    float em0 = emean[0], em1 = emean[1];
    int stride = gridDim.x * blockDim.x;
    for (int k = blockIdx.x * blockDim.x + threadIdx.x; k < nE; k += stride) {
        int a = ei[k];
        int b = ei[nE + k];
        float2 at = ea[k];
        float2 pa = pred[a];
        float2 pb = pred[b];
        float Pa, Qa, Pb, Qb;
        msg_compute(pa, pb, at, es0, es1, em0, em1, Pa, Qa);
        msg_compute(pb, pa, at, es0, es1, em0, em1, Pb, Qb);
        unsafeAtomicAdd(&calc[2 * (size_t)a],     Pa);
        unsafeAtomicAdd(&calc[2 * (size_t)a + 1], Qa);
        unsafeAtomicAdd(&calc[2 * (size_t)b],     Pb);
        unsafeAtomicAdd(&calc[2 * (size_t)b + 1], Qb);
    }
}

__global__ void pass3_phys(const float2* __restrict__ calc, Scalars* sc, int n)
{
    double s = 0.0;
    int stride = gridDim.x * blockDim.x;
    for (int i = blockIdx.x * blockDim.x + threadIdx.x; i < n; i += stride) {
        float2 c = calc[i];
        s += (double)c.x * (double)c.x + (double)c.y * (double)c.y;
    }
    s = blockReduceSum(s);
    if (threadIdx.x == 0) atomicAdd(&sc->phys_sum, s);
}

__global__ void finalize_kernel(const Scalars* __restrict__ sc, float* __restrict__ out, int n)
{
    if (threadIdx.x == 0 && blockIdx.x == 0) {
        double mse  = sc->mse_num / (sc->mse_den + 1e-6);
        double phys = sc->phys_sum / (2.0 * (double)n);
        double pv   = (sc->pv_cnt > 0.0) ? (sc->pv_sum / fmax(sc->pv_cnt, 1.0)) : 0.0;
        double total = 0.8 * mse + 0.2 * phys + 0.1 * pv;
        out[0] = (float)total;
        out[1] = (float)mse;
        out[2] = (float)phys;
        out[3] = (float)pv;
    }
}

extern "C" void kernel_launch(void* const* d_in, const int* in_sizes, int n_in,
                              void* d_out, int out_size, void* d_ws, size_t ws_size,
                              hipStream_t stream) {
    const float2* pred   = (const float2*)d_in[0];
    const float4* ty     = (const float4*)d_in[1];
    const float4* mask   = (const float4*)d_in[2];
    const int*    ei     = (const int*)d_in[3];
    const float2* ea     = (const float2*)d_in[4];
    const int*    bus    = (const int*)d_in[5];
    const float*  tvm    = (const float*)d_in[6];
    const float*  xymean = (const float*)d_in[7];
    const float*  xystd  = (const float*)d_in[8];
    const float*  emean  = (const float*)d_in[9];
    const float*  estd   = (const float*)d_in[10];
    float* out = (float*)d_out;

    int n  = in_sizes[0] / 2;   // nodes
    int nE = in_sizes[3] / 2;   // edges

    char* basep = (char*)d_ws;
    Scalars* sc = (Scalars*)basep;
    size_t head = 64;
    float* calc = (float*)(basep + head);
    head += (size_t)2 * n * sizeof(float);
    head = (head + 15) & ~(size_t)15;

    const int BLK = 256, GRID = 2048;

    // ---- fast tier: PB=11, 16B records, cap=CAPF ----
    int nbinsN = (n + PSZ_NEW - 1) >> PB_NEW;
    size_t slotsN = (size_t)K3GRID * nbinsN;
    size_t offN = head + slotsN * sizeof(unsigned int);
    offN = (offN + 15) & ~(size_t)15;
    size_t needN = offN + slotsN * (size_t)CAPF * sizeof(float4);
    bool useNew = (n <= (1 << 20)) && (nbinsN <= MAXBINS) && (needN <= ws_size);

    zero_scalars_kernel<<<1, 64, 0, stream>>>((double*)sc);

    if (useNew) {
        unsigned int* gcnt = (unsigned int*)(basep + head);
        float4* bkt = (float4*)(basep + offN);

        zero_f32_kernel<<<1024, 256, 0, stream>>>(calc, 2 * n);  // overflow accumulator
        scatter_gb2<<<K3GRID, K3BLK, 0, stream>>>(ei, ea, pred, emean, estd,
                                                  bkt, gcnt, calc, nE, nbinsN);
        gather_fused<<<nbinsN, K4BLK, 0, stream>>>(bkt, gcnt, pred, calc, ty, mask,
                                                   bus, tvm, xymean, xystd, sc, n, nbinsN);
        finalize_kernel<<<1, 64, 0, stream>>>(sc, out, n);
        return;
    }

    // ---- OLD tiers: 8B records ----
    bool fits_pack = (n <= (1 << 20)) && (nE <= (1 << 22));
    int nbins11 = (n + 2047) >> 11;
    int nbins12 = (n + 4095) >> 12;
    size_t needA = head + (size_t)K3GRID * nbins11 * 4 + 16 +
                   (size_t)K3GRID * nbins11 * 64 * 8;
    size_t needB = head + (size_t)K3GRID * nbins12 * 4 + 16 +
                   (size_t)K3GRID * nbins12 * 96 * 8;

    int tier = 2;
    if (fits_pack && nbins11 <= MAXBINS && needA <= ws_size) tier = 0;
    else if (fits_pack && nbins12 <= MAXBINS && needB <= ws_size) tier = 1;

    if (tier == 0 || tier == 1) {
        int pb    = (tier == 0) ? 11 : 12;
        int cap   = (tier == 0) ? 64 : 96;
        int nbins = (tier == 0) ? nbins11 : nbins12;

        size_t off = head;
        unsigned int* gcnt = (unsigned int*)(basep + off);
        off += (size_t)K3GRID * nbins * sizeof(unsigned int);
        off = (off + 15) & ~(size_t)15;
        unsigned long long* bkt = (unsigned long long*)(basep + off);

        pass1_nodes<<<GRID, BLK, 0, stream>>>(pred, ty, mask, bus, tvm, xymean, xystd,
                                              (float2*)calc, sc, n, /*seed=*/0);
        scatter_idx<<<K3GRID, K3BLK, 0, stream>>>(ei, ea, pred, emean, estd,
                                                  bkt, gcnt, calc, nE, nbins, cap, pb);
        if (tier == 0)
            gather_t<11, 64><<<nbins, K4BLK, 0, stream>>>(bkt, gcnt, pred, ea, emean, estd,
                                                          calc, ty, xymean, xystd, sc, n, nbins);
        else
            gather_t<12, 96><<<nbins, K4BLK, 0, stream>>>(bkt, gcnt, pred, ea, emean, estd,
                                                          calc, ty, xymean, xystd, sc, n, nbins);
        finalize_kernel<<<1, 64, 0, stream>>>(sc, out, n);
    } else {
        pass1_nodes<<<GRID, BLK, 0, stream>>>(pred, ty, mask, bus, tvm, xymean, xystd,
                                              (float2*)calc, sc, n, /*seed=*/1);
        pass2_edges<<<GRID, BLK, 0, stream>>>(ei, ea, pred, emean, estd, calc, nE);
        pass3_phys<<<GRID, BLK, 0, stream>>>((const float2*)calc, sc, n);
        finalize_kernel<<<1, 64, 0, stream>>>(sc, out, n);
    }
}